// Round 1
// baseline (894.211 us; speedup 1.0000x reference)
//
#include <hip/hip_runtime.h>
#include <math.h>

#define BATCH 512
#define VEN 30000
#define VCN 20000
#define KT 100
#define HID 512
#define DIM 300
#define VENP 30080   // padded to 128
#define VCNP 20096
#define KDP 320      // DIM padded to mult of 64

typedef float f32x4 __attribute__((ext_vector_type(4)));
typedef short bf16x8 __attribute__((ext_vector_type(8)));
typedef unsigned short u16x8 __attribute__((ext_vector_type(8)));
typedef unsigned short u16x4 __attribute__((ext_vector_type(4)));

// ---------------- workspace layout (float offsets) ----------------
#define WS_H1_EN   0
#define WS_H2_EN   (WS_H1_EN + 262144)
#define WS_H1_CN   (WS_H2_EN + 262144)
#define WS_H2_CN   (WS_H1_CN + 262144)
#define WS_ROWS_EN (WS_H2_CN + 262144)
#define WS_ROWS_CN (WS_ROWS_EN + 1536)
#define WS_SCAL    (WS_ROWS_CN + 1536)
#define ZERO_FLOATS (WS_SCAL + 64)
// BIG aliased region: phase 1 = bf16 copies of x_en/x_cn; phase 2 = WEP/TEP + BT/THP
#define WS_BIG     ZERO_FLOATS
#define XB_EN      WS_BIG                       // 512*30000 u16 = 7,680,000 f
#define XB_CN      (WS_BIG + 7680000)           // 512*20000 u16 = 5,120,000 f
#define WEP_EN     WS_BIG                       // 4,812,800 f
#define WEP_CN     (WS_BIG + 4812800)           // 3,215,360 f
#define TEP        (WS_BIG + 4812800 + 3215360) // 20,480 f
#define BT_EN      (WS_BIG + 8048640)           // 30080*128 u16 = 1,925,120 f
#define BT_CN      (BT_EN + 1925120)            // 20096*128 u16 = 1,286,144 f
#define THP_EN     (BT_CN + 1286144)            // 512*128 u16 = 32,768 f
#define THP_CN     (THP_EN + 32768)
#define AFTER_BIG  (WS_BIG + 12800000)
#define W1T_EN     AFTER_BIG                    // 7,680,000 f
#define W1T_CN     (W1T_EN + 7680000)           // 5,120,000 f
#define W2T_EN     (W1T_CN + 5120000)           // 131072 f
#define W2T_CN     (W2T_EN + 131072)
#define H1B_EN     (W2T_CN + 131072)
#define H1B_CN     (H1B_EN + 131072)
#define WN2_EN     (H1B_CN + 131072)            // 30080
#define WN2_CN     (WN2_EN + 30080)             // 20096
#define TN2        (WN2_CN + 20096)             // 128
#define WS_TNBUF   (TN2 + 128)                  // 51200
#define WS_TNT     (WS_TNBUF + 51200)           // 30000
#define WS_CTOP    (WS_TNT + 30000)             // 10000
#define WS_COLSUM_EN (WS_CTOP + 10000)          // 128
#define WS_COLSUM_CN (WS_COLSUM_EN + 128)

// ---------------- output layout (float offsets) ----------------
#define OUT_THETA_EN 5
#define OUT_THETA_CN (OUT_THETA_EN + 51200)
#define OUT_BETA_EN  (OUT_THETA_CN + 51200)
#define OUT_BETA_CN  (OUT_BETA_EN + 3000000)

__device__ __forceinline__ float waveReduceSum(float v) {
    #pragma unroll
    for (int o = 32; o > 0; o >>= 1) v += __shfl_down(v, o);
    return v;
}

__device__ __forceinline__ unsigned short f2bf(float f) {
    unsigned int u = __float_as_uint(f);
    u = (u + 0x7FFFu + ((u >> 16) & 1u)) >> 16;   // RNE
    return (unsigned short)u;
}

// f32 -> bf16 elementwise cast, 8 elems/thread (32B read / 16B write per lane)
__global__ __launch_bounds__(256)
void cast_bf16_kernel(const float* __restrict__ src, unsigned short* __restrict__ dst, int n)
{
    int i = (blockIdx.x * 256 + threadIdx.x) * 8;
    if (i < n) {
        float4 a = *(const float4*)&src[i];
        float4 b = *(const float4*)&src[i + 4];
        u16x8 o = { f2bf(a.x), f2bf(a.y), f2bf(a.z), f2bf(a.w),
                    f2bf(b.x), f2bf(b.y), f2bf(b.z), f2bf(b.w) };
        *(u16x8*)&dst[i] = o;
    }
}

// ================= bf16 MFMA GEMM (NT) =================
// A: AF32 ? fp32 (converted during staging) : bf16. B: bf16 [N][ldB] k-major.
// MODE 0: C[M][N] fp32 atomicAdd (split-K).
// MODE 2: beta epilogue.
template <int MODE, int AF32>
__global__ __launch_bounds__(256)
void mfma_gemm_nt(const void* __restrict__ Av, const unsigned short* __restrict__ B,
                  float* __restrict__ C, int M, int N, int K, int ldA, int ldB, int chunkK,
                  int Mreal, const float* __restrict__ an2, const float* __restrict__ bn2)
{
    __shared__ __align__(16) unsigned short As[128 * 40];
    __shared__ __align__(16) unsigned short Bs[128 * 40];
    const int tid = threadIdx.x;
    const int m0 = blockIdx.x * 128, n0 = blockIdx.y * 128;
    const int kStart = blockIdx.z * chunkK;
    const int kEnd = min(kStart + chunkK, K);

    const int wave = tid >> 6, lane = tid & 63;
    const int wm = (wave & 1) * 64, wn = (wave >> 1) * 64;
    const int l15 = lane & 15, quad = lane >> 4;

    const int srow = tid >> 1;
    const int scol = (tid & 1) * 16;

    f32x4 acc[4][4];
    #pragma unroll
    for (int i = 0; i < 4; ++i)
        #pragma unroll
        for (int j = 0; j < 4; ++j)
            acc[i][j] = (f32x4){0.f, 0.f, 0.f, 0.f};

    const u16x8 z8 = {0,0,0,0,0,0,0,0};

    for (int k0 = kStart; k0 < kEnd; k0 += 32) {
        int kA = k0 + scol;
        if (AF32) {
            const float* pa = (const float*)Av + (size_t)(m0 + srow) * ldA + kA;
            float4 f0 = {0,0,0,0}, f1 = {0,0,0,0}, f2 = {0,0,0,0}, f3 = {0,0,0,0};
            if (kA < kEnd) {   // K multiples of 16 -> whole 16-chunk valid
                f0 = *(const float4*)(pa);
                f1 = *(const float4*)(pa + 4);
                f2 = *(const float4*)(pa + 8);
                f3 = *(const float4*)(pa + 12);
            }
            u16x8 o0 = { f2bf(f0.x), f2bf(f0.y), f2bf(f0.z), f2bf(f0.w),
                         f2bf(f1.x), f2bf(f1.y), f2bf(f1.z), f2bf(f1.w) };
            u16x8 o1 = { f2bf(f2.x), f2bf(f2.y), f2bf(f2.z), f2bf(f2.w),
                         f2bf(f3.x), f2bf(f3.y), f2bf(f3.z), f2bf(f3.w) };
            *(u16x8*)&As[srow * 40 + scol]     = o0;
            *(u16x8*)&As[srow * 40 + scol + 8] = o1;
        } else {
            const unsigned short* pa = (const unsigned short*)Av + (size_t)(m0 + srow) * ldA + kA;
            u16x8 a0 = (kA     < kEnd) ? *(const u16x8*)(pa)     : z8;
            u16x8 a1 = (kA + 8 < kEnd) ? *(const u16x8*)(pa + 8) : z8;
            *(u16x8*)&As[srow * 40 + scol]     = a0;
            *(u16x8*)&As[srow * 40 + scol + 8] = a1;
        }
        {
            const unsigned short* pb = B + (size_t)(n0 + srow) * ldB + kA;
            u16x8 b0 = (kA     < kEnd) ? *(const u16x8*)(pb)     : z8;
            u16x8 b1 = (kA + 8 < kEnd) ? *(const u16x8*)(pb + 8) : z8;
            *(u16x8*)&Bs[srow * 40 + scol]     = b0;
            *(u16x8*)&Bs[srow * 40 + scol + 8] = b1;
        }
        __syncthreads();
        bf16x8 af[4], bfr[4];
        #pragma unroll
        for (int mi = 0; mi < 4; ++mi)
            af[mi] = *(const bf16x8*)&As[(wm + mi * 16 + l15) * 40 + quad * 8];
        #pragma unroll
        for (int ni = 0; ni < 4; ++ni)
            bfr[ni] = *(const bf16x8*)&Bs[(wn + ni * 16 + l15) * 40 + quad * 8];
        #pragma unroll
        for (int mi = 0; mi < 4; ++mi)
            #pragma unroll
            for (int ni = 0; ni < 4; ++ni)
                acc[mi][ni] = __builtin_amdgcn_mfma_f32_16x16x32_bf16(af[mi], bfr[ni], acc[mi][ni], 0, 0, 0);
        __syncthreads();
    }

    if (MODE == 0) {
        #pragma unroll
        for (int mi = 0; mi < 4; ++mi)
            #pragma unroll
            for (int ni = 0; ni < 4; ++ni)
                #pragma unroll
                for (int i = 0; i < 4; ++i) {
                    int m = m0 + wm + mi * 16 + quad * 4 + i;
                    int n = n0 + wn + ni * 16 + l15;
                    atomicAdd(&C[(size_t)m * N + n], acc[mi][ni][i]);
                }
    } else {
        #pragma unroll
        for (int mi = 0; mi < 4; ++mi)
            #pragma unroll
            for (int ni = 0; ni < 4; ++ni)
                #pragma unroll
                for (int i = 0; i < 4; ++i) {
                    int m = m0 + wm + mi * 16 + quad * 4 + i;
                    int n = n0 + wn + ni * 16 + l15;
                    if (m < Mreal && n < KT) {
                        float sq = an2[m] + bn2[n] - 2.f * acc[mi][ni][i];
                        C[(size_t)n * Mreal + m] = __expf(-sqrtf(fmaxf(sq, 0.f)));
                    }
                }
    }
}

// ============ recon MFMA: r = betaT[V][K] x thetaPad[B][K]; fused loss sums ============
__global__ __launch_bounds__(256)
void recon_mfma_kernel(const unsigned short* __restrict__ A, const unsigned short* __restrict__ B,
                       const float* __restrict__ x, int V, float* __restrict__ rows)
{
    __shared__ __align__(16) unsigned short As[128 * 40];
    __shared__ __align__(16) unsigned short Bs[128 * 40];
    const int tid = threadIdx.x;
    const int m0 = blockIdx.x * 128, n0 = blockIdx.y * 128;
    const int wave = tid >> 6, lane = tid & 63;
    const int wm = (wave & 1) * 64, wn = (wave >> 1) * 64;
    const int l15 = lane & 15, quad = lane >> 4;
    const int srow = tid >> 1, scol = (tid & 1) * 16;

    f32x4 acc[4][4];
    #pragma unroll
    for (int i = 0; i < 4; ++i)
        #pragma unroll
        for (int j = 0; j < 4; ++j)
            acc[i][j] = (f32x4){0.f, 0.f, 0.f, 0.f};

    for (int k0 = 0; k0 < 128; k0 += 32) {
        int kA = k0 + scol;
        *(u16x8*)&As[srow * 40 + scol]     = *(const u16x8*)(A + (size_t)(m0 + srow) * 128 + kA);
        *(u16x8*)&As[srow * 40 + scol + 8] = *(const u16x8*)(A + (size_t)(m0 + srow) * 128 + kA + 8);
        *(u16x8*)&Bs[srow * 40 + scol]     = *(const u16x8*)(B + (size_t)(n0 + srow) * 128 + kA);
        *(u16x8*)&Bs[srow * 40 + scol + 8] = *(const u16x8*)(B + (size_t)(n0 + srow) * 128 + kA + 8);
        __syncthreads();
        bf16x8 af[4], bfr[4];
        #pragma unroll
        for (int mi = 0; mi < 4; ++mi)
            af[mi] = *(const bf16x8*)&As[(wm + mi * 16 + l15) * 40 + quad * 8];
        #pragma unroll
        for (int ni = 0; ni < 4; ++ni)
            bfr[ni] = *(const bf16x8*)&Bs[(wn + ni * 16 + l15) * 40 + quad * 8];
        #pragma unroll
        for (int mi = 0; mi < 4; ++mi)
            #pragma unroll
            for (int ni = 0; ni < 4; ++ni)
                acc[mi][ni] = __builtin_amdgcn_mfma_f32_16x16x32_bf16(af[mi], bfr[ni], acc[mi][ni], 0, 0, 0);
        __syncthreads();
    }

    #pragma unroll
    for (int ni = 0; ni < 4; ++ni) {
        int b = n0 + wn + ni * 16 + l15;
        float tse = 0.f, tsxr = 0.f, tsx = 0.f;
        #pragma unroll
        for (int mi = 0; mi < 4; ++mi) {
            int v0 = m0 + wm + mi * 16 + quad * 4;
            if (v0 + 3 < V) {
                float4 xv = *(const float4*)&x[(size_t)b * V + v0];
                float xa[4] = {xv.x, xv.y, xv.z, xv.w};
                #pragma unroll
                for (int i = 0; i < 4; ++i) {
                    float r = acc[mi][ni][i];
                    tse += __expf(r);
                    tsxr += xa[i] * r;
                    tsx  += xa[i];
                }
            } else {
                #pragma unroll
                for (int i = 0; i < 4; ++i) {
                    int v = v0 + i;
                    if (v < V) {
                        float xv1 = x[(size_t)b * V + v];
                        float r = acc[mi][ni][i];
                        tse += __expf(r); tsxr += xv1 * r; tsx += xv1;
                    }
                }
            }
        }
        tse  += __shfl_xor(tse, 16);  tse  += __shfl_xor(tse, 32);
        tsxr += __shfl_xor(tsxr, 16); tsxr += __shfl_xor(tsxr, 32);
        tsx  += __shfl_xor(tsx, 16);  tsx  += __shfl_xor(tsx, 32);
        if (quad == 0) {
            atomicAdd(&rows[b], tse);
            atomicAdd(&rows[512 + b], tsxr);
            atomicAdd(&rows[1024 + b], tsx);
        }
    }
}

// ================= cast / transpose kernels =================
__global__ __launch_bounds__(256)
void transpose_cast_kernel(const float* __restrict__ src, unsigned short* __restrict__ dst,
                           int K, int N)
{
    __shared__ float tile[32][33];
    int kb = blockIdx.x * 32, nb = blockIdx.y * 32;
    int tx = threadIdx.x & 31, ty4 = threadIdx.x >> 5;
    #pragma unroll
    for (int j = 0; j < 4; ++j) {
        int k = kb + ty4 * 4 + j;
        tile[ty4 * 4 + j][tx] = (k < K) ? src[(size_t)k * N + nb + tx] : 0.f;
    }
    __syncthreads();
    #pragma unroll
    for (int j = 0; j < 4; ++j) {
        int n = nb + ty4 * 4 + j;
        int k = kb + tx;
        if (k < K) dst[(size_t)n * K + k] = f2bf(tile[tx][ty4 * 4 + j]);
    }
}

// fused: word_emb [V][300] f32 -> [Vp][320] bf16 zero-padded + row sqnorm
__global__ void padcast_sqnorm_kernel(const float* __restrict__ src, unsigned short* __restrict__ dst,
                                      float* __restrict__ n2, int V)
{
    int m = blockIdx.x, tid = threadIdx.x;   // 64 threads
    float sq = 0.f;
    #pragma unroll
    for (int j = 0; j < 5; ++j) {
        int k = tid + j * 64;
        float v = (m < V && k < DIM) ? src[(size_t)m * DIM + k] : 0.f;
        dst[(size_t)m * KDP + k] = f2bf(v);
        sq += v * v;
    }
    sq = waveReduceSum(sq);
    if (tid == 0) n2[m] = sq;
}

// fused: normalize beta in place (f32, out buffer) + build bt [Vp][128] bf16
__global__ __launch_bounds__(256)
void normbeta_bt_kernel(float* __restrict__ beta, const float* __restrict__ cs,
                        unsigned short* __restrict__ bt, int V)
{
    int v = blockIdx.x * 64 + (threadIdx.x & 63);
    int kq = threadIdx.x >> 6;   // 0..3
    unsigned short tmp[32];
    #pragma unroll
    for (int j = 0; j < 32; ++j) {
        int k = kq * 32 + j;
        float val = 0.f;
        if (k < KT && v < V) {
            val = beta[(size_t)k * V + v] * (1.0f / cs[k]);
            beta[(size_t)k * V + v] = val;
        }
        tmp[j] = f2bf(val);
    }
    #pragma unroll
    for (int q = 0; q < 4; ++q)
        *(u16x8*)&bt[(size_t)v * 128 + kq * 32 + q * 8] = *(u16x8*)&tmp[q * 8];
}

__global__ void theta_pad_kernel(const float* __restrict__ theta, unsigned short* __restrict__ thp)
{
    int idx = blockIdx.x * 256 + threadIdx.x;  // 65536 total
    int b = idx >> 7, k = idx & 127;
    thp[idx] = f2bf(k < KT ? theta[b * KT + k] : 0.f);
}

__global__ __launch_bounds__(256)
void colsum_kernel(const float* __restrict__ bta, float* __restrict__ cs, int V)
{
    int k = blockIdx.x, tid = threadIdx.x;
    float s = 0.f;
    for (int v = tid; v < V; v += 256) s += bta[(size_t)k * V + v];
    s = waveReduceSum(s);
    __shared__ float cw[4];
    if ((tid & 63) == 0) cw[tid >> 6] = s;
    __syncthreads();
    if (tid == 0) cs[k] = cw[0] + cw[1] + cw[2] + cw[3];
}

__global__ void bias_softplus_bf16_kernel(const float* __restrict__ src, const float* __restrict__ b,
                                          unsigned short* __restrict__ dst, int n)
{
    int i = blockIdx.x * 256 + threadIdx.x;
    if (i < n) {
        float x = src[i] + b[i & (HID - 1)];
        float sp = fmaxf(x, 0.f) + log1pf(__expf(-fabsf(x)));
        dst[i] = f2bf(sp);
    }
}

__global__ void bias_softplus_f32_kernel(float* __restrict__ y, const float* __restrict__ b, int n)
{
    int i = blockIdx.x * 256 + threadIdx.x;
    if (i < n) {
        float x = y[i] + b[i & (HID - 1)];
        y[i] = fmaxf(x, 0.f) + log1pf(__expf(-fabsf(x)));
    }
}

// ================= encoder head =================
__global__ __launch_bounds__(128)
void encoder_head_kernel(const float* __restrict__ h2, const float* __restrict__ Wmu,
                         const float* __restrict__ bmu, const float* __restrict__ Wlv,
                         const float* __restrict__ blv, const float* __restrict__ eps,
                         float* __restrict__ theta_out, float* __restrict__ kl_accum)
{
    int i = blockIdx.x, tid = threadIdx.x;
    __shared__ float hrow[HID];
    __shared__ float sred[128];
    #pragma unroll
    for (int j = 0; j < 4; ++j) hrow[tid + 128 * j] = h2[i * HID + tid + 128 * j];
    __syncthreads();
    float mu = 0.f, lv = 0.f;
    if (tid < KT) {
        #pragma unroll 8
        for (int h = 0; h < HID; ++h) {
            float hv = hrow[h];
            mu += hv * Wmu[h * KT + tid];
            lv += hv * Wlv[h * KT + tid];
        }
        mu += bmu[tid]; lv += blv[tid];
    }
    float z = (tid < KT) ? (mu + eps[i * KT + tid] * __expf(0.5f * lv)) : -3.0e38f;
    sred[tid] = z; __syncthreads();
    for (int s = 64; s > 0; s >>= 1) { if (tid < s) sred[tid] = fmaxf(sred[tid], sred[tid + s]); __syncthreads(); }
    float zmax = sred[0]; __syncthreads();
    float e = (tid < KT) ? __expf(z - zmax) : 0.f;
    sred[tid] = e; __syncthreads();
    for (int s = 64; s > 0; s >>= 1) { if (tid < s) sred[tid] += sred[tid + s]; __syncthreads(); }
    float esum = sred[0]; __syncthreads();
    if (tid < KT) theta_out[i * KT + tid] = e / esum;
    float kterm = (tid < KT) ? 0.5f * (__expf(lv) + mu * mu - 1.f - lv) : 0.f;
    sred[tid] = kterm; __syncthreads();
    for (int s = 64; s > 0; s >>= 1) { if (tid < s) sred[tid] += sred[tid + s]; __syncthreads(); }
    if (tid == 0) atomicAdd(kl_accum, sred[0]);
}

__global__ __launch_bounds__(256)
void recon_finalize_kernel(const float* __restrict__ rows_en, const float* __restrict__ rows_cn,
                           float* __restrict__ scal)
{
    const float* rows = (blockIdx.x == 0) ? rows_en : rows_cn;
    int tid = threadIdx.x;
    float s = 0.f;
    for (int r = tid; r < 512; r += 256) {
        float se = rows[r], sxr = rows[512 + r], sx = rows[1024 + r];
        s += __logf(se) * sx - sxr;
    }
    s = waveReduceSum(s);
    __shared__ float cw[4];
    if ((tid & 63) == 0) cw[tid >> 6] = s;
    __syncthreads();
    if (tid == 0) scal[5 + blockIdx.x] = cw[0] + cw[1] + cw[2] + cw[3];
}

// ================= contrastive =================
__global__ __launch_bounds__(128)
void contrast_prep_kernel(const float* __restrict__ theta_en, const float* __restrict__ theta_cn,
                          float* __restrict__ tn)
{
    int i = blockIdx.x, tid = threadIdx.x;
    const float* src = ((i & 1) == 0) ? theta_en : theta_cn;
    float val = (tid < KT) ? src[i * KT + tid] : 0.f;
    __shared__ float sred[128];
    sred[tid] = val * val; __syncthreads();
    for (int s = 64; s > 0; s >>= 1) { if (tid < s) sred[tid] += sred[tid + s]; __syncthreads(); }
    float inv = 1.0f / fmaxf(sqrtf(sred[0]), 1e-8f);
    if (tid < KT) tn[i * KT + tid] = val * inv;
}

__global__ __launch_bounds__(256)
void contrast_main_kernel(const float* __restrict__ tn, const int* __restrict__ cid,
                          float* __restrict__ scal)
{
    int i = blockIdx.x, tid = threadIdx.x;
    __shared__ __align__(16) float ti[KT];
    if (tid < KT) ti[tid] = tn[i * KT + tid];
    __syncthreads();
    int ci = cid[i];
    bool vi = ci > 0;
    float pos = 0.f, neg = 0.f, pcnt = 0.f;
    for (int j = tid; j < 512; j += 256) {
        if (j == i) continue;
        float s = 0.f;
        const float4* tj = reinterpret_cast<const float4*>(&tn[j * KT]);
        #pragma unroll
        for (int q = 0; q < 25; ++q) {
            float4 t4 = tj[q];
            s += ti[4 * q] * t4.x + ti[4 * q + 1] * t4.y + ti[4 * q + 2] * t4.z + ti[4 * q + 3] * t4.w;
        }
        float E = __expf(s);
        neg += E;
        if (vi && cid[j] == ci) { pos += E; pcnt += 1.f; }
    }
    pos = waveReduceSum(pos); neg = waveReduceSum(neg); pcnt = waveReduceSum(pcnt);
    __shared__ float cw[3][4];
    int w = tid >> 6;
    if ((tid & 63) == 0) { cw[0][w] = pos; cw[1][w] = neg; cw[2][w] = pcnt; }
    __syncthreads();
    if (tid == 0) {
        float P = 0.f, N = 0.f, PC = 0.f;
        for (int q = 0; q < 4; ++q) { P += cw[0][q]; N += cw[1][q]; PC += cw[2][q]; }
        if (vi && PC > 0.f) {
            atomicAdd(&scal[2], -__logf(P / (P + N + 1e-8f)));
            atomicAdd(&scal[3], 1.0f);
        }
    }
}

// ================= alignment / sinkhorn =================
__global__ void norm_rows_kernel(const float* __restrict__ A, float* __restrict__ out, int cols)
{
    int r = blockIdx.x, tid = threadIdx.x;
    float s = 0.f;
    for (int d = tid; d < cols; d += 64) { float a = A[r * cols + d]; s += a * a; }
    s = waveReduceSum(s);
    s = __shfl(s, 0);
    float inv = 1.0f / fmaxf(sqrtf(s), 1e-8f);
    for (int d = tid; d < cols; d += 64) out[r * cols + d] = A[r * cols + d] * inv;
}

__global__ __launch_bounds__(128)
void ctopic_kernel(const float* __restrict__ tnt, float* __restrict__ C)
{
    int i = blockIdx.x, tid = threadIdx.x;
    __shared__ float ti[DIM];
    for (int d = tid; d < DIM; d += 128) ti[d] = tnt[i * DIM + d];
    __syncthreads();
    for (int j = tid; j < KT; j += 128) {
        float s = 0.f;
        for (int d = 0; d < DIM; ++d) s += ti[d] * tnt[j * DIM + d];
        C[i * KT + j] = 1.0f - s;
    }
}

// register-resident sinkhorn: 2 waves, thread t owns row t (K) and col t (K^T)
__global__ __launch_bounds__(128, 1)
void sinkhorn_kernel(const float* __restrict__ C, float* __restrict__ scal)
{
    __shared__ __align__(16) float ld[100 * 101];
    __shared__ __align__(16) float ub[128], vb[128];
    __shared__ float cw[2];
    const int tid = threadIdx.x;

    for (int i = tid; i < 10000; i += 128) {
        int r = i / 100, c = i - r * 100;
        ld[r * 101 + c] = C[i];
    }
    ub[tid] = 1.f; vb[tid] = 1.f;
    __syncthreads();

    float kr[100], kc[100];
    if (tid < 100) {
        #pragma unroll
        for (int j = 0; j < 100; ++j) kr[j] = __expf(-10.f * ld[tid * 101 + j]);
        #pragma unroll
        for (int j = 0; j < 100; ++j) kc[j] = __expf(-10.f * ld[j * 101 + tid]);
    }

    for (int it = 0; it < 50; ++it) {
        if (tid < 100) {
            float s = 0.f;
            #pragma unroll
            for (int q = 0; q < 25; ++q) {
                float4 v4 = *(const float4*)&vb[q * 4];
                s += kr[q*4]*v4.x + kr[q*4+1]*v4.y + kr[q*4+2]*v4.z + kr[q*4+3]*v4.w;
            }
            ub[tid] = 0.01f / (s + 1e-8f);
        }
        __syncthreads();
        if (tid < 100) {
            float s = 0.f;
            #pragma unroll
            for (int q = 0; q < 25; ++q) {
                float4 u4 = *(const float4*)&ub[q * 4];
                s += kc[q*4]*u4.x + kc[q*4+1]*u4.y + kc[q*4+2]*u4.z + kc[q*4+3]*u4.w;
            }
            vb[tid] = 0.01f / (s + 1e-8f);
        }
        __syncthreads();
    }

    // loss = sum_ij u_i K_ij v_j C_ij
    float part = 0.f;
    if (tid < 100) {
        float u = ub[tid];
        #pragma unroll
        for (int q = 0; q < 25; ++q) {
            float4 v4 = *(const float4*)&vb[q * 4];
            float va[4] = {v4.x, v4.y, v4.z, v4.w};
            #pragma unroll
            for (int e = 0; e < 4; ++e) {
                int j = q * 4 + e;
                part += u * kr[j] * va[e] * ld[tid * 101 + j];
            }
        }
    }
    part = waveReduceSum(part);
    if ((tid & 63) == 0) cw[tid >> 6] = part;
    __syncthreads();
    if (tid == 0) scal[4] = cw[0] + cw[1];
}

__global__ void final_combine_kernel(const float* __restrict__ scal, float* __restrict__ out)
{
    if (threadIdx.x == 0 && blockIdx.x == 0) {
        const float invB = 1.0f / 512.0f;
        float tm_en = scal[5] * invB + scal[0] * invB;
        float tm_cn = scal[6] * invB + scal[1] * invB;
        float contrast = scal[2] / (scal[3] + 1e-8f);
        float align = scal[4];
        out[0] = tm_en + tm_cn + contrast + align;
        out[1] = tm_en;
        out[2] = tm_cn;
        out[3] = contrast;
        out[4] = align;
    }
}

// ================= launch =================
extern "C" void kernel_launch(void* const* d_in, const int* in_sizes, int n_in,
                              void* d_out_v, int out_size, void* d_ws, size_t ws_size,
                              hipStream_t stream)
{
    const float* x_en   = (const float*)d_in[0];
    const float* x_cn   = (const float*)d_in[1];
    const int*   cid    = (const int*)  d_in[2];
    const float* eps_en = (const float*)d_in[3];
    const float* eps_cn = (const float*)d_in[4];
    const float* W1_en  = (const float*)d_in[5];
    const float* b1_en  = (const float*)d_in[6];
    const float* W2_en  = (const float*)d_in[7];
    const float* b2_en  = (const float*)d_in[8];
    const float* Wmu_en = (const float*)d_in[9];
    const float* bmu_en = (const float*)d_in[10];
    const float* Wlv_en = (const float*)d_in[11];
    const float* blv_en = (const float*)d_in[12];
    const float* W1_cn  = (const float*)d_in[13];
    const float* b1_cn  = (const float*)d_in[14];
    const float* W2_cn  = (const float*)d_in[15];
    const float* b2_cn  = (const float*)d_in[16];
    const float* Wmu_cn = (const float*)d_in[17];
    const float* bmu_cn = (const float*)d_in[18];
    const float* Wlv_cn = (const float*)d_in[19];
    const float* blv_cn = (const float*)d_in[20];
    const float* we_en  = (const float*)d_in[21];
    const float* we_cn  = (const float*)d_in[22];
    const float* te     = (const float*)d_in[23];
    float* out = (float*)d_out_v;
    float* ws  = (float*)d_ws;

    unsigned short* w1t_en = (unsigned short*)(ws + W1T_EN);
    unsigned short* w1t_cn = (unsigned short*)(ws + W1T_CN);
    unsigned short* w2t_en = (unsigned short*)(ws + W2T_EN);
    unsigned short* w2t_cn = (unsigned short*)(ws + W2T_CN);
    unsigned short* h1b_en = (unsigned short*)(ws + H1B_EN);
    unsigned short* h1b_cn = (unsigned short*)(ws + H1B_CN);
    unsigned short* xb_en  = (unsigned short*)(ws + XB_EN);
    unsigned short* xb_cn  = (unsigned short*)(ws + XB_CN);
    unsigned short* wep_en = (unsigned short*)(ws + WEP_EN);
    unsigned short* wep_cn = (unsigned short*)(ws + WEP_CN);
    unsigned short* tep    = (unsigned short*)(ws + TEP);
    unsigned short* bt_en  = (unsigned short*)(ws + BT_EN);
    unsigned short* bt_cn  = (unsigned short*)(ws + BT_CN);
    unsigned short* thp_en = (unsigned short*)(ws + THP_EN);
    unsigned short* thp_cn = (unsigned short*)(ws + THP_CN);

    hipMemsetAsync(d_ws, 0, (size_t)ZERO_FLOATS * sizeof(float), stream);

    // ---- phase 1: encoders (x pre-cast to bf16 in BIG region; GEMM1 is pure-bf16) ----
    cast_bf16_kernel<<<7500, 256, 0, stream>>>(x_en, xb_en, BATCH * VEN);
    cast_bf16_kernel<<<5000, 256, 0, stream>>>(x_cn, xb_cn, BATCH * VCN);

    transpose_cast_kernel<<<dim3(938, 16), 256, 0, stream>>>(W1_en, w1t_en, VEN, HID);
    transpose_cast_kernel<<<dim3(625, 16), 256, 0, stream>>>(W1_cn, w1t_cn, VCN, HID);
    transpose_cast_kernel<<<dim3(16, 16), 256, 0, stream>>>(W2_en, w2t_en, HID, HID);
    transpose_cast_kernel<<<dim3(16, 16), 256, 0, stream>>>(W2_cn, w2t_cn, HID, HID);

    mfma_gemm_nt<0, 0><<<dim3(4, 4, 32), 256, 0, stream>>>(xb_en, w1t_en, ws + WS_H1_EN,
        BATCH, HID, VEN, VEN, VEN, 960, 0, nullptr, nullptr);
    mfma_gemm_nt<0, 0><<<dim3(4, 4, 32), 256, 0, stream>>>(xb_cn, w1t_cn, ws + WS_H1_CN,
        BATCH, HID, VCN, VCN, VCN, 640, 0, nullptr, nullptr);

    bias_softplus_bf16_kernel<<<1024, 256, 0, stream>>>(ws + WS_H1_EN, b1_en, h1b_en, 262144);
    bias_softplus_bf16_kernel<<<1024, 256, 0, stream>>>(ws + WS_H1_CN, b1_cn, h1b_cn, 262144);

    mfma_gemm_nt<0, 0><<<dim3(4, 4, 8), 256, 0, stream>>>(h1b_en, w2t_en, ws + WS_H2_EN,
        BATCH, HID, HID, HID, HID, 64, 0, nullptr, nullptr);
    mfma_gemm_nt<0, 0><<<dim3(4, 4, 8), 256, 0, stream>>>(h1b_cn, w2t_cn, ws + WS_H2_CN,
        BATCH, HID, HID, HID, HID, 64, 0, nullptr, nullptr);

    bias_softplus_f32_kernel<<<1024, 256, 0, stream>>>(ws + WS_H2_EN, b2_en, 262144);
    bias_softplus_f32_kernel<<<1024, 256, 0, stream>>>(ws + WS_H2_CN, b2_cn, 262144);

    encoder_head_kernel<<<BATCH, 128, 0, stream>>>(ws + WS_H2_EN, Wmu_en, bmu_en, Wlv_en, blv_en,
                                                   eps_en, out + OUT_THETA_EN, ws + WS_SCAL + 0);
    encoder_head_kernel<<<BATCH, 128, 0, stream>>>(ws + WS_H2_CN, Wmu_cn, bmu_cn, Wlv_cn, blv_cn,
                                                   eps_cn, out + OUT_THETA_CN, ws + WS_SCAL + 1);

    // ---- phase 2: beta path (BIG region reused; all phase-1 reads of xb complete) ----
    padcast_sqnorm_kernel<<<VENP, 64, 0, stream>>>(we_en, wep_en, ws + WN2_EN, VEN);
    padcast_sqnorm_kernel<<<VCNP, 64, 0, stream>>>(we_cn, wep_cn, ws + WN2_CN, VCN);
    padcast_sqnorm_kernel<<<128, 64, 0, stream>>>(te, tep, ws + TN2, KT);

    mfma_gemm_nt<2, 0><<<dim3(235, 1, 1), 256, 0, stream>>>(wep_en, tep, out + OUT_BETA_EN,
        VENP, 128, KDP, KDP, KDP, KDP, VEN, ws + WN2_EN, ws + TN2);
    mfma_gemm_nt<2, 0><<<dim3(157, 1, 1), 256, 0, stream>>>(wep_cn, tep, out + OUT_BETA_CN,
        VCNP, 128, KDP, KDP, KDP, KDP, VCN, ws + WN2_CN, ws + TN2);

    colsum_kernel<<<KT, 256, 0, stream>>>(out + OUT_BETA_EN, ws + WS_COLSUM_EN, VEN);
    colsum_kernel<<<KT, 256, 0, stream>>>(out + OUT_BETA_CN, ws + WS_COLSUM_CN, VCN);

    normbeta_bt_kernel<<<VENP / 64, 256, 0, stream>>>(out + OUT_BETA_EN, ws + WS_COLSUM_EN, bt_en, VEN);
    normbeta_bt_kernel<<<VCNP / 64, 256, 0, stream>>>(out + OUT_BETA_CN, ws + WS_COLSUM_CN, bt_cn, VCN);

    // ---- recon via MFMA ----
    theta_pad_kernel<<<256, 256, 0, stream>>>(out + OUT_THETA_EN, thp_en);
    theta_pad_kernel<<<256, 256, 0, stream>>>(out + OUT_THETA_CN, thp_cn);

    recon_mfma_kernel<<<dim3(VENP / 128, 4), 256, 0, stream>>>(bt_en, thp_en, x_en, VEN, ws + WS_ROWS_EN);
    recon_mfma_kernel<<<dim3(VCNP / 128, 4), 256, 0, stream>>>(bt_cn, thp_cn, x_cn, VCN, ws + WS_ROWS_CN);
    recon_finalize_kernel<<<2, 256, 0, stream>>>(ws + WS_ROWS_EN, ws + WS_ROWS_CN, ws + WS_SCAL);

    // ---- contrastive ----
    contrast_prep_kernel<<<BATCH, 128, 0, stream>>>(out + OUT_THETA_EN, out + OUT_THETA_CN, ws + WS_TNBUF);
    contrast_main_kernel<<<BATCH, 256, 0, stream>>>(ws + WS_TNBUF, cid, ws + WS_SCAL);

    // ---- alignment ----
    norm_rows_kernel<<<KT, 64, 0, stream>>>(te, ws + WS_TNT, DIM);
    ctopic_kernel<<<KT, 128, 0, stream>>>(ws + WS_TNT, ws + WS_CTOP);
    sinkhorn_kernel<<<1, 128, 0, stream>>>(ws + WS_CTOP, ws + WS_SCAL);

    final_combine_kernel<<<1, 64, 0, stream>>>(ws + WS_SCAL, out);
}

// Round 3
// 891.165 us; speedup vs baseline: 1.0034x; 1.0034x over previous
//
#include <hip/hip_runtime.h>
#include <math.h>

#define BATCH 512
#define VEN 30000
#define VCN 20000
#define KT 100
#define HID 512
#define DIM 300
#define VENP 30080   // padded to 128
#define VCNP 20096
#define KDP 320      // DIM padded to mult of 64
#define VENK 30080   // K padded to mult of 64 for gemm1
#define VCNK 20096

typedef float f32x4 __attribute__((ext_vector_type(4)));
typedef short bf16x8 __attribute__((ext_vector_type(8)));
typedef unsigned short u16x8 __attribute__((ext_vector_type(8)));
typedef unsigned int u32;

// ---------------- workspace layout (float offsets) ----------------
#define WS_H1_EN   0
#define WS_H2_EN   (WS_H1_EN + 262144)
#define WS_H1_CN   (WS_H2_EN + 262144)
#define WS_H2_CN   (WS_H1_CN + 262144)
#define WS_ROWS_EN (WS_H2_CN + 262144)
#define WS_ROWS_CN (WS_ROWS_EN + 1536)
#define WS_SCAL    (WS_ROWS_CN + 1536)
#define ZERO_FLOATS (WS_SCAL + 64)
// BIG aliased region: phase 1 = padded bf16 copies of x; phase 2 = WEP/TEP + BT/THP
#define WS_BIG     ZERO_FLOATS
#define XB_EN      WS_BIG                       // 512*30080 u16 = 7,700,480 f
#define XB_CN      (WS_BIG + 7700480)           // 512*20096 u16 = 5,144,576 f
#define WEP_EN     WS_BIG                       // 4,812,800 f
#define WEP_CN     (WS_BIG + 4812800)           // 3,215,360 f
#define TEP        (WS_BIG + 4812800 + 3215360) // 20,480 f
#define BT_EN      (WS_BIG + 8048640)           // 30080*128 u16 = 1,925,120 f
#define BT_CN      (BT_EN + 1925120)            // 20096*128 u16 = 1,286,144 f
#define THP_EN     (BT_CN + 1286144)            // 512*128 u16 = 32,768 f
#define THP_CN     (THP_EN + 32768)
#define AFTER_BIG  (WS_BIG + 12845056)
#define W1T_EN     AFTER_BIG                    // 512*30080 u16 = 7,700,480 f
#define W1T_CN     (W1T_EN + 7700480)           // 512*20096 u16 = 5,144,576 f
#define W2T_EN     (W1T_CN + 5144576)
#define W2T_CN     (W2T_EN + 131072)
#define H1B_EN     (W2T_CN + 131072)
#define H1B_CN     (H1B_EN + 131072)
#define WN2_EN     (H1B_CN + 131072)            // 30080
#define WN2_CN     (WN2_EN + 30080)             // 20096
#define TN2        (WN2_CN + 20096)             // 128
#define WS_TNBUF   (TN2 + 128)                  // 51200
#define WS_TNT     (WS_TNBUF + 51200)           // 30000
#define WS_CTOP    (WS_TNT + 30000)             // 10000
#define WS_COLSUM_EN (WS_CTOP + 10000)          // 128
#define WS_COLSUM_CN (WS_COLSUM_EN + 128)

// ---------------- output layout (float offsets) ----------------
#define OUT_THETA_EN 5
#define OUT_THETA_CN (OUT_THETA_EN + 51200)
#define OUT_BETA_EN  (OUT_THETA_CN + 51200)
#define OUT_BETA_CN  (OUT_BETA_EN + 3000000)

__device__ __forceinline__ float waveReduceSum(float v) {
    #pragma unroll
    for (int o = 32; o > 0; o >>= 1) v += __shfl_down(v, o);
    return v;
}

__device__ __forceinline__ unsigned short f2bf(float f) {
    unsigned int u = __float_as_uint(f);
    u = (u + 0x7FFFu + ((u >> 16) & 1u)) >> 16;   // RNE
    return (unsigned short)u;
}

// async global->LDS, 16 B per lane: LDS dest = wave-uniform base + lane*16
__device__ __forceinline__ void gl2lds16(const unsigned short* g, unsigned short* l) {
    __builtin_amdgcn_global_load_lds(
        (const __attribute__((address_space(1))) u32*)g,
        (__attribute__((address_space(3))) u32*)l, 16, 0, 0);
}

// f32 -> bf16 cast with column zero-padding: dst [rows][colsPad]
__global__ __launch_bounds__(256)
void cast_pad_bf16_kernel(const float* __restrict__ src, unsigned short* __restrict__ dst,
                          int cols, int colsPad)
{
    int row = blockIdx.y;
    int col = (blockIdx.x * 256 + threadIdx.x) * 8;
    if (col >= colsPad) return;
    u16x8 o = {0,0,0,0,0,0,0,0};
    if (col < cols) {   // cols % 8 == 0 -> chunk fully valid
        float4 a = *(const float4*)&src[(size_t)row * cols + col];
        float4 b = *(const float4*)&src[(size_t)row * cols + col + 4];
        o = (u16x8){ f2bf(a.x), f2bf(a.y), f2bf(a.z), f2bf(a.w),
                     f2bf(b.x), f2bf(b.y), f2bf(b.z), f2bf(b.w) };
    }
    *(u16x8*)&dst[(size_t)row * colsPad + col] = o;
}

// ============ GEMM1: async-staged bf16 MFMA NT, split-K atomic ============
// A [M][ldA] bf16 zero-padded (ldA = K, mult of 64); B [N][ldB] likewise.
// C [M][N] f32 atomicAdd. Tile 128x128, BK=64, 256 threads (4 waves).
// LDS linear [128][64] with chunk XOR-swizzle c ^= (row&7) applied on the
// GLOBAL source address at stage time and on the ds_read address (T2/m173).
__global__ __launch_bounds__(256)
void gemm1_async(const unsigned short* __restrict__ A, const unsigned short* __restrict__ B,
                 float* __restrict__ C, int N, int ldA, int ldB, int chunkK, int K)
{
    __shared__ __align__(16) unsigned short As[128 * 64];
    __shared__ __align__(16) unsigned short Bs[128 * 64];
    const int tid = threadIdx.x;
    const int m0 = blockIdx.x * 128, n0 = blockIdx.y * 128;
    const int kStart = blockIdx.z * chunkK;
    const int kEnd = min(kStart + chunkK, K);   // multiples of 64

    const int wave = tid >> 6, lane = tid & 63;
    const int wm = (wave & 1) * 64, wn = (wave >> 1) * 64;
    const int l15 = lane & 15, quad = lane >> 4;

    // staging geometry: each wave-instruction covers 8 rows x 64 elems (1 KB)
    const int rl = lane >> 3;                 // row within 8-row group
    const int cs = (lane & 7) ^ rl;           // swizzled source chunk (8 elems)

    f32x4 acc[4][4];
    #pragma unroll
    for (int i = 0; i < 4; ++i)
        #pragma unroll
        for (int j = 0; j < 4; ++j)
            acc[i][j] = (f32x4){0.f, 0.f, 0.f, 0.f};

    for (int k0 = kStart; k0 < kEnd; k0 += 64) {
        #pragma unroll
        for (int j = 0; j < 4; ++j) {
            int seg = wave * 4 + j;                       // 0..15
            int r = seg * 8 + rl;                         // 0..127
            gl2lds16(A + (size_t)(m0 + r) * ldA + k0 + cs * 8, &As[seg * 512]);
            gl2lds16(B + (size_t)(n0 + r) * ldB + k0 + cs * 8, &Bs[seg * 512]);
        }
        asm volatile("s_waitcnt vmcnt(0)" ::: "memory");
        __syncthreads();

        #pragma unroll
        for (int kh = 0; kh < 2; ++kh) {
            bf16x8 af[4], bfr[4];
            #pragma unroll
            for (int mi = 0; mi < 4; ++mi) {
                int r = wm + mi * 16 + l15;
                af[mi] = *(const bf16x8*)&As[r * 64 + (((kh << 2) | quad) ^ (r & 7)) * 8];
            }
            #pragma unroll
            for (int ni = 0; ni < 4; ++ni) {
                int r = wn + ni * 16 + l15;
                bfr[ni] = *(const bf16x8*)&Bs[r * 64 + (((kh << 2) | quad) ^ (r & 7)) * 8];
            }
            #pragma unroll
            for (int mi = 0; mi < 4; ++mi)
                #pragma unroll
                for (int ni = 0; ni < 4; ++ni)
                    acc[mi][ni] = __builtin_amdgcn_mfma_f32_16x16x32_bf16(af[mi], bfr[ni], acc[mi][ni], 0, 0, 0);
        }
        __syncthreads();
    }

    #pragma unroll
    for (int mi = 0; mi < 4; ++mi)
        #pragma unroll
        for (int ni = 0; ni < 4; ++ni)
            #pragma unroll
            for (int i = 0; i < 4; ++i) {
                int m = m0 + wm + mi * 16 + quad * 4 + i;
                int n = n0 + wn + ni * 16 + l15;
                atomicAdd(&C[(size_t)m * N + n], acc[mi][ni][i]);
            }
}

// ================= bf16 MFMA GEMM (NT) =================
// MODE 0: C[M][N] fp32 atomicAdd (split-K).  MODE 2: beta epilogue.
template <int MODE, int AF32>
__global__ __launch_bounds__(256)
void mfma_gemm_nt(const void* __restrict__ Av, const unsigned short* __restrict__ B,
                  float* __restrict__ C, int M, int N, int K, int ldA, int ldB, int chunkK,
                  int Mreal, const float* __restrict__ an2, const float* __restrict__ bn2)
{
    __shared__ __align__(16) unsigned short As[128 * 40];
    __shared__ __align__(16) unsigned short Bs[128 * 40];
    const int tid = threadIdx.x;
    const int m0 = blockIdx.x * 128, n0 = blockIdx.y * 128;
    const int kStart = blockIdx.z * chunkK;
    const int kEnd = min(kStart + chunkK, K);

    const int wave = tid >> 6, lane = tid & 63;
    const int wm = (wave & 1) * 64, wn = (wave >> 1) * 64;
    const int l15 = lane & 15, quad = lane >> 4;

    const int srow = tid >> 1;
    const int scol = (tid & 1) * 16;

    f32x4 acc[4][4];
    #pragma unroll
    for (int i = 0; i < 4; ++i)
        #pragma unroll
        for (int j = 0; j < 4; ++j)
            acc[i][j] = (f32x4){0.f, 0.f, 0.f, 0.f};

    const u16x8 z8 = {0,0,0,0,0,0,0,0};

    for (int k0 = kStart; k0 < kEnd; k0 += 32) {
        int kA = k0 + scol;
        if (AF32) {
            const float* pa = (const float*)Av + (size_t)(m0 + srow) * ldA + kA;
            float4 f0 = {0,0,0,0}, f1 = {0,0,0,0}, f2 = {0,0,0,0}, f3 = {0,0,0,0};
            if (kA < kEnd) {
                f0 = *(const float4*)(pa);
                f1 = *(const float4*)(pa + 4);
                f2 = *(const float4*)(pa + 8);
                f3 = *(const float4*)(pa + 12);
            }
            u16x8 o0 = { f2bf(f0.x), f2bf(f0.y), f2bf(f0.z), f2bf(f0.w),
                         f2bf(f1.x), f2bf(f1.y), f2bf(f1.z), f2bf(f1.w) };
            u16x8 o1 = { f2bf(f2.x), f2bf(f2.y), f2bf(f2.z), f2bf(f2.w),
                         f2bf(f3.x), f2bf(f3.y), f2bf(f3.z), f2bf(f3.w) };
            *(u16x8*)&As[srow * 40 + scol]     = o0;
            *(u16x8*)&As[srow * 40 + scol + 8] = o1;
        } else {
            const unsigned short* pa = (const unsigned short*)Av + (size_t)(m0 + srow) * ldA + kA;
            u16x8 a0 = (kA     < kEnd) ? *(const u16x8*)(pa)     : z8;
            u16x8 a1 = (kA + 8 < kEnd) ? *(const u16x8*)(pa + 8) : z8;
            *(u16x8*)&As[srow * 40 + scol]     = a0;
            *(u16x8*)&As[srow * 40 + scol + 8] = a1;
        }
        {
            const unsigned short* pb = B + (size_t)(n0 + srow) * ldB + kA;
            u16x8 b0 = (kA     < kEnd) ? *(const u16x8*)(pb)     : z8;
            u16x8 b1 = (kA + 8 < kEnd) ? *(const u16x8*)(pb + 8) : z8;
            *(u16x8*)&Bs[srow * 40 + scol]     = b0;
            *(u16x8*)&Bs[srow * 40 + scol + 8] = b1;
        }
        __syncthreads();
        bf16x8 af[4], bfr[4];
        #pragma unroll
        for (int mi = 0; mi < 4; ++mi)
            af[mi] = *(const bf16x8*)&As[(wm + mi * 16 + l15) * 40 + quad * 8];
        #pragma unroll
        for (int ni = 0; ni < 4; ++ni)
            bfr[ni] = *(const bf16x8*)&Bs[(wn + ni * 16 + l15) * 40 + quad * 8];
        #pragma unroll
        for (int mi = 0; mi < 4; ++mi)
            #pragma unroll
            for (int ni = 0; ni < 4; ++ni)
                acc[mi][ni] = __builtin_amdgcn_mfma_f32_16x16x32_bf16(af[mi], bfr[ni], acc[mi][ni], 0, 0, 0);
        __syncthreads();
    }

    if (MODE == 0) {
        #pragma unroll
        for (int mi = 0; mi < 4; ++mi)
            #pragma unroll
            for (int ni = 0; ni < 4; ++ni)
                #pragma unroll
                for (int i = 0; i < 4; ++i) {
                    int m = m0 + wm + mi * 16 + quad * 4 + i;
                    int n = n0 + wn + ni * 16 + l15;
                    atomicAdd(&C[(size_t)m * N + n], acc[mi][ni][i]);
                }
    } else {
        #pragma unroll
        for (int mi = 0; mi < 4; ++mi)
            #pragma unroll
            for (int ni = 0; ni < 4; ++ni)
                #pragma unroll
                for (int i = 0; i < 4; ++i) {
                    int m = m0 + wm + mi * 16 + quad * 4 + i;
                    int n = n0 + wn + ni * 16 + l15;
                    if (m < Mreal && n < KT) {
                        float sq = an2[m] + bn2[n] - 2.f * acc[mi][ni][i];
                        C[(size_t)n * Mreal + m] = __expf(-sqrtf(fmaxf(sq, 0.f)));
                    }
                }
    }
}

// ============ recon MFMA: r = betaT[V][K] x thetaPad[B][K]; fused loss sums ============
__global__ __launch_bounds__(256)
void recon_mfma_kernel(const unsigned short* __restrict__ A, const unsigned short* __restrict__ B,
                       const float* __restrict__ x, int V, float* __restrict__ rows)
{
    __shared__ __align__(16) unsigned short As[128 * 40];
    __shared__ __align__(16) unsigned short Bs[128 * 40];
    const int tid = threadIdx.x;
    const int m0 = blockIdx.x * 128, n0 = blockIdx.y * 128;
    const int wave = tid >> 6, lane = tid & 63;
    const int wm = (wave & 1) * 64, wn = (wave >> 1) * 64;
    const int l15 = lane & 15, quad = lane >> 4;
    const int srow = tid >> 1, scol = (tid & 1) * 16;

    f32x4 acc[4][4];
    #pragma unroll
    for (int i = 0; i < 4; ++i)
        #pragma unroll
        for (int j = 0; j < 4; ++j)
            acc[i][j] = (f32x4){0.f, 0.f, 0.f, 0.f};

    for (int k0 = 0; k0 < 128; k0 += 32) {
        int kA = k0 + scol;
        *(u16x8*)&As[srow * 40 + scol]     = *(const u16x8*)(A + (size_t)(m0 + srow) * 128 + kA);
        *(u16x8*)&As[srow * 40 + scol + 8] = *(const u16x8*)(A + (size_t)(m0 + srow) * 128 + kA + 8);
        *(u16x8*)&Bs[srow * 40 + scol]     = *(const u16x8*)(B + (size_t)(n0 + srow) * 128 + kA);
        *(u16x8*)&Bs[srow * 40 + scol + 8] = *(const u16x8*)(B + (size_t)(n0 + srow) * 128 + kA + 8);
        __syncthreads();
        bf16x8 af[4], bfr[4];
        #pragma unroll
        for (int mi = 0; mi < 4; ++mi)
            af[mi] = *(const bf16x8*)&As[(wm + mi * 16 + l15) * 40 + quad * 8];
        #pragma unroll
        for (int ni = 0; ni < 4; ++ni)
            bfr[ni] = *(const bf16x8*)&Bs[(wn + ni * 16 + l15) * 40 + quad * 8];
        #pragma unroll
        for (int mi = 0; mi < 4; ++mi)
            #pragma unroll
            for (int ni = 0; ni < 4; ++ni)
                acc[mi][ni] = __builtin_amdgcn_mfma_f32_16x16x32_bf16(af[mi], bfr[ni], acc[mi][ni], 0, 0, 0);
        __syncthreads();
    }

    #pragma unroll
    for (int ni = 0; ni < 4; ++ni) {
        int b = n0 + wn + ni * 16 + l15;
        float tse = 0.f, tsxr = 0.f, tsx = 0.f;
        #pragma unroll
        for (int mi = 0; mi < 4; ++mi) {
            int v0 = m0 + wm + mi * 16 + quad * 4;
            if (v0 + 3 < V) {
                float4 xv = *(const float4*)&x[(size_t)b * V + v0];
                float xa[4] = {xv.x, xv.y, xv.z, xv.w};
                #pragma unroll
                for (int i = 0; i < 4; ++i) {
                    float r = acc[mi][ni][i];
                    tse += __expf(r);
                    tsxr += xa[i] * r;
                    tsx  += xa[i];
                }
            } else {
                #pragma unroll
                for (int i = 0; i < 4; ++i) {
                    int v = v0 + i;
                    if (v < V) {
                        float xv1 = x[(size_t)b * V + v];
                        float r = acc[mi][ni][i];
                        tse += __expf(r); tsxr += xv1 * r; tsx += xv1;
                    }
                }
            }
        }
        tse  += __shfl_xor(tse, 16);  tse  += __shfl_xor(tse, 32);
        tsxr += __shfl_xor(tsxr, 16); tsxr += __shfl_xor(tsxr, 32);
        tsx  += __shfl_xor(tsx, 16);  tsx  += __shfl_xor(tsx, 32);
        if (quad == 0) {
            atomicAdd(&rows[b], tse);
            atomicAdd(&rows[512 + b], tsxr);
            atomicAdd(&rows[1024 + b], tsx);
        }
    }
}

// ================= cast / transpose kernels =================
__global__ __launch_bounds__(256)
void transpose_cast_kernel(const float* __restrict__ src, unsigned short* __restrict__ dst,
                           int K, int N, int Kp)
{
    __shared__ float tile[32][33];
    int kb = blockIdx.x * 32, nb = blockIdx.y * 32;
    int tx = threadIdx.x & 31, ty4 = threadIdx.x >> 5;
    #pragma unroll
    for (int j = 0; j < 4; ++j) {
        int k = kb + ty4 * 4 + j;
        tile[ty4 * 4 + j][tx] = (k < K) ? src[(size_t)k * N + nb + tx] : 0.f;
    }
    __syncthreads();
    #pragma unroll
    for (int j = 0; j < 4; ++j) {
        int n = nb + ty4 * 4 + j;
        int k = kb + tx;
        if (k < Kp) dst[(size_t)n * Kp + k] = f2bf(tile[tx][ty4 * 4 + j]);
    }
}

// fused: word_emb [V][300] f32 -> [Vp][320] bf16 zero-padded + row sqnorm
__global__ void padcast_sqnorm_kernel(const float* __restrict__ src, unsigned short* __restrict__ dst,
                                      float* __restrict__ n2, int V)
{
    int m = blockIdx.x, tid = threadIdx.x;   // 64 threads
    float sq = 0.f;
    #pragma unroll
    for (int j = 0; j < 5; ++j) {
        int k = tid + j * 64;
        float v = (m < V && k < DIM) ? src[(size_t)m * DIM + k] : 0.f;
        dst[(size_t)m * KDP + k] = f2bf(v);
        sq += v * v;
    }
    sq = waveReduceSum(sq);
    if (tid == 0) n2[m] = sq;
}

// fused: normalize beta in place (f32, out buffer) + build bt [Vp][128] bf16
__global__ __launch_bounds__(256)
void normbeta_bt_kernel(float* __restrict__ beta, const float* __restrict__ cs,
                        unsigned short* __restrict__ bt, int V)
{
    int v = blockIdx.x * 64 + (threadIdx.x & 63);
    int kq = threadIdx.x >> 6;   // 0..3
    unsigned short tmp[32];
    #pragma unroll
    for (int j = 0; j < 32; ++j) {
        int k = kq * 32 + j;
        float val = 0.f;
        if (k < KT && v < V) {
            val = beta[(size_t)k * V + v] * (1.0f / cs[k]);
            beta[(size_t)k * V + v] = val;
        }
        tmp[j] = f2bf(val);
    }
    #pragma unroll
    for (int q = 0; q < 4; ++q)
        *(u16x8*)&bt[(size_t)v * 128 + kq * 32 + q * 8] = *(u16x8*)&tmp[q * 8];
}

__global__ void theta_pad_kernel(const float* __restrict__ theta, unsigned short* __restrict__ thp)
{
    int idx = blockIdx.x * 256 + threadIdx.x;  // 65536 total
    int b = idx >> 7, k = idx & 127;
    thp[idx] = f2bf(k < KT ? theta[b * KT + k] : 0.f);
}

__global__ __launch_bounds__(256)
void colsum_kernel(const float* __restrict__ bta, float* __restrict__ cs, int V)
{
    int k = blockIdx.x, tid = threadIdx.x;
    float s = 0.f;
    for (int v = tid; v < V; v += 256) s += bta[(size_t)k * V + v];
    s = waveReduceSum(s);
    __shared__ float cw[4];
    if ((tid & 63) == 0) cw[tid >> 6] = s;
    __syncthreads();
    if (tid == 0) cs[k] = cw[0] + cw[1] + cw[2] + cw[3];
}

__global__ void bias_softplus_bf16_kernel(const float* __restrict__ src, const float* __restrict__ b,
                                          unsigned short* __restrict__ dst, int n)
{
    int i = blockIdx.x * 256 + threadIdx.x;
    if (i < n) {
        float x = src[i] + b[i & (HID - 1)];
        float sp = fmaxf(x, 0.f) + log1pf(__expf(-fabsf(x)));
        dst[i] = f2bf(sp);
    }
}

__global__ void bias_softplus_f32_kernel(float* __restrict__ y, const float* __restrict__ b, int n)
{
    int i = blockIdx.x * 256 + threadIdx.x;
    if (i < n) {
        float x = y[i] + b[i & (HID - 1)];
        y[i] = fmaxf(x, 0.f) + log1pf(__expf(-fabsf(x)));
    }
}

// ================= encoder head =================
__global__ __launch_bounds__(128)
void encoder_head_kernel(const float* __restrict__ h2, const float* __restrict__ Wmu,
                         const float* __restrict__ bmu, const float* __restrict__ Wlv,
                         const float* __restrict__ blv, const float* __restrict__ eps,
                         float* __restrict__ theta_out, float* __restrict__ kl_accum)
{
    int i = blockIdx.x, tid = threadIdx.x;
    __shared__ float hrow[HID];
    __shared__ float sred[128];
    #pragma unroll
    for (int j = 0; j < 4; ++j) hrow[tid + 128 * j] = h2[i * HID + tid + 128 * j];
    __syncthreads();
    float mu = 0.f, lv = 0.f;
    if (tid < KT) {
        #pragma unroll 8
        for (int h = 0; h < HID; ++h) {
            float hv = hrow[h];
            mu += hv * Wmu[h * KT + tid];
            lv += hv * Wlv[h * KT + tid];
        }
        mu += bmu[tid]; lv += blv[tid];
    }
    float z = (tid < KT) ? (mu + eps[i * KT + tid] * __expf(0.5f * lv)) : -3.0e38f;
    sred[tid] = z; __syncthreads();
    for (int s = 64; s > 0; s >>= 1) { if (tid < s) sred[tid] = fmaxf(sred[tid], sred[tid + s]); __syncthreads(); }
    float zmax = sred[0]; __syncthreads();
    float e = (tid < KT) ? __expf(z - zmax) : 0.f;
    sred[tid] = e; __syncthreads();
    for (int s = 64; s > 0; s >>= 1) { if (tid < s) sred[tid] += sred[tid + s]; __syncthreads(); }
    float esum = sred[0]; __syncthreads();
    if (tid < KT) theta_out[i * KT + tid] = e / esum;
    float kterm = (tid < KT) ? 0.5f * (__expf(lv) + mu * mu - 1.f - lv) : 0.f;
    sred[tid] = kterm; __syncthreads();
    for (int s = 64; s > 0; s >>= 1) { if (tid < s) sred[tid] += sred[tid + s]; __syncthreads(); }
    if (tid == 0) atomicAdd(kl_accum, sred[0]);
}

__global__ __launch_bounds__(256)
void recon_finalize_kernel(const float* __restrict__ rows_en, const float* __restrict__ rows_cn,
                           float* __restrict__ scal)
{
    const float* rows = (blockIdx.x == 0) ? rows_en : rows_cn;
    int tid = threadIdx.x;
    float s = 0.f;
    for (int r = tid; r < 512; r += 256) {
        float se = rows[r], sxr = rows[512 + r], sx = rows[1024 + r];
        s += __logf(se) * sx - sxr;
    }
    s = waveReduceSum(s);
    __shared__ float cw[4];
    if ((tid & 63) == 0) cw[tid >> 6] = s;
    __syncthreads();
    if (tid == 0) scal[5 + blockIdx.x] = cw[0] + cw[1] + cw[2] + cw[3];
}

// ================= contrastive =================
__global__ __launch_bounds__(128)
void contrast_prep_kernel(const float* __restrict__ theta_en, const float* __restrict__ theta_cn,
                          float* __restrict__ tn)
{
    int i = blockIdx.x, tid = threadIdx.x;
    const float* src = ((i & 1) == 0) ? theta_en : theta_cn;
    float val = (tid < KT) ? src[i * KT + tid] : 0.f;
    __shared__ float sred[128];
    sred[tid] = val * val; __syncthreads();
    for (int s = 64; s > 0; s >>= 1) { if (tid < s) sred[tid] += sred[tid + s]; __syncthreads(); }
    float inv = 1.0f / fmaxf(sqrtf(sred[0]), 1e-8f);
    if (tid < KT) tn[i * KT + tid] = val * inv;
}

__global__ __launch_bounds__(256)
void contrast_main_kernel(const float* __restrict__ tn, const int* __restrict__ cid,
                          float* __restrict__ scal)
{
    int i = blockIdx.x, tid = threadIdx.x;
    __shared__ __align__(16) float ti[KT];
    if (tid < KT) ti[tid] = tn[i * KT + tid];
    __syncthreads();
    int ci = cid[i];
    bool vi = ci > 0;
    float pos = 0.f, neg = 0.f, pcnt = 0.f;
    for (int j = tid; j < 512; j += 256) {
        if (j == i) continue;
        float s = 0.f;
        const float4* tj = reinterpret_cast<const float4*>(&tn[j * KT]);
        #pragma unroll
        for (int q = 0; q < 25; ++q) {
            float4 t4 = tj[q];
            s += ti[4 * q] * t4.x + ti[4 * q + 1] * t4.y + ti[4 * q + 2] * t4.z + ti[4 * q + 3] * t4.w;
        }
        float E = __expf(s);
        neg += E;
        if (vi && cid[j] == ci) { pos += E; pcnt += 1.f; }
    }
    pos = waveReduceSum(pos); neg = waveReduceSum(neg); pcnt = waveReduceSum(pcnt);
    __shared__ float cw[3][4];
    int w = tid >> 6;
    if ((tid & 63) == 0) { cw[0][w] = pos; cw[1][w] = neg; cw[2][w] = pcnt; }
    __syncthreads();
    if (tid == 0) {
        float P = 0.f, N = 0.f, PC = 0.f;
        for (int q = 0; q < 4; ++q) { P += cw[0][q]; N += cw[1][q]; PC += cw[2][q]; }
        if (vi && PC > 0.f) {
            atomicAdd(&scal[2], -__logf(P / (P + N + 1e-8f)));
            atomicAdd(&scal[3], 1.0f);
        }
    }
}

// ================= alignment / sinkhorn =================
__global__ void norm_rows_kernel(const float* __restrict__ A, float* __restrict__ out, int cols)
{
    int r = blockIdx.x, tid = threadIdx.x;
    float s = 0.f;
    for (int d = tid; d < cols; d += 64) { float a = A[r * cols + d]; s += a * a; }
    s = waveReduceSum(s);
    s = __shfl(s, 0);
    float inv = 1.0f / fmaxf(sqrtf(s), 1e-8f);
    for (int d = tid; d < cols; d += 64) out[r * cols + d] = A[r * cols + d] * inv;
}

__global__ __launch_bounds__(128)
void ctopic_kernel(const float* __restrict__ tnt, float* __restrict__ C)
{
    int i = blockIdx.x, tid = threadIdx.x;
    __shared__ float ti[DIM];
    for (int d = tid; d < DIM; d += 128) ti[d] = tnt[i * DIM + d];
    __syncthreads();
    for (int j = tid; j < KT; j += 128) {
        float s = 0.f;
        for (int d = 0; d < DIM; ++d) s += ti[d] * tnt[j * DIM + d];
        C[i * KT + j] = 1.0f - s;
    }
}

// register-resident sinkhorn: 2 waves, thread t owns row t (K) and col t (K^T)
__global__ __launch_bounds__(128, 1)
void sinkhorn_kernel(const float* __restrict__ C, float* __restrict__ scal)
{
    __shared__ __align__(16) float ld[100 * 101];
    __shared__ __align__(16) float ub[128], vb[128];
    __shared__ float cw[2];
    const int tid = threadIdx.x;

    for (int i = tid; i < 10000; i += 128) {
        int r = i / 100, c = i - r * 100;
        ld[r * 101 + c] = C[i];
    }
    ub[tid] = 1.f; vb[tid] = 1.f;
    __syncthreads();

    float kr[100], kc[100];
    if (tid < 100) {
        #pragma unroll
        for (int j = 0; j < 100; ++j) kr[j] = __expf(-10.f * ld[tid * 101 + j]);
        #pragma unroll
        for (int j = 0; j < 100; ++j) kc[j] = __expf(-10.f * ld[j * 101 + tid]);
    }

    for (int it = 0; it < 50; ++it) {
        if (tid < 100) {
            float s = 0.f;
            #pragma unroll
            for (int q = 0; q < 25; ++q) {
                float4 v4 = *(const float4*)&vb[q * 4];
                s += kr[q*4]*v4.x + kr[q*4+1]*v4.y + kr[q*4+2]*v4.z + kr[q*4+3]*v4.w;
            }
            ub[tid] = 0.01f / (s + 1e-8f);
        }
        __syncthreads();
        if (tid < 100) {
            float s = 0.f;
            #pragma unroll
            for (int q = 0; q < 25; ++q) {
                float4 u4 = *(const float4*)&ub[q * 4];
                s += kc[q*4]*u4.x + kc[q*4+1]*u4.y + kc[q*4+2]*u4.z + kc[q*4+3]*u4.w;
            }
            vb[tid] = 0.01f / (s + 1e-8f);
        }
        __syncthreads();
    }

    // loss = sum_ij u_i K_ij v_j C_ij
    float part = 0.f;
    if (tid < 100) {
        float u = ub[tid];
        #pragma unroll
        for (int q = 0; q < 25; ++q) {
            float4 v4 = *(const float4*)&vb[q * 4];
            float va[4] = {v4.x, v4.y, v4.z, v4.w};
            #pragma unroll
            for (int e = 0; e < 4; ++e) {
                int j = q * 4 + e;
                part += u * kr[j] * va[e] * ld[tid * 101 + j];
            }
        }
    }
    part = waveReduceSum(part);
    if ((tid & 63) == 0) cw[tid >> 6] = part;
    __syncthreads();
    if (tid == 0) scal[4] = cw[0] + cw[1];
}

__global__ void final_combine_kernel(const float* __restrict__ scal, float* __restrict__ out)
{
    if (threadIdx.x == 0 && blockIdx.x == 0) {
        const float invB = 1.0f / 512.0f;
        float tm_en = scal[5] * invB + scal[0] * invB;
        float tm_cn = scal[6] * invB + scal[1] * invB;
        float contrast = scal[2] / (scal[3] + 1e-8f);
        float align = scal[4];
        out[0] = tm_en + tm_cn + contrast + align;
        out[1] = tm_en;
        out[2] = tm_cn;
        out[3] = contrast;
        out[4] = align;
    }
}

// ================= launch =================
extern "C" void kernel_launch(void* const* d_in, const int* in_sizes, int n_in,
                              void* d_out_v, int out_size, void* d_ws, size_t ws_size,
                              hipStream_t stream)
{
    const float* x_en   = (const float*)d_in[0];
    const float* x_cn   = (const float*)d_in[1];
    const int*   cid    = (const int*)  d_in[2];
    const float* eps_en = (const float*)d_in[3];
    const float* eps_cn = (const float*)d_in[4];
    const float* W1_en  = (const float*)d_in[5];
    const float* b1_en  = (const float*)d_in[6];
    const float* W2_en  = (const float*)d_in[7];
    const float* b2_en  = (const float*)d_in[8];
    const float* Wmu_en = (const float*)d_in[9];
    const float* bmu_en = (const float*)d_in[10];
    const float* Wlv_en = (const float*)d_in[11];
    const float* blv_en = (const float*)d_in[12];
    const float* W1_cn  = (const float*)d_in[13];
    const float* b1_cn  = (const float*)d_in[14];
    const float* W2_cn  = (const float*)d_in[15];
    const float* b2_cn  = (const float*)d_in[16];
    const float* Wmu_cn = (const float*)d_in[17];
    const float* bmu_cn = (const float*)d_in[18];
    const float* Wlv_cn = (const float*)d_in[19];
    const float* blv_cn = (const float*)d_in[20];
    const float* we_en  = (const float*)d_in[21];
    const float* we_cn  = (const float*)d_in[22];
    const float* te     = (const float*)d_in[23];
    float* out = (float*)d_out_v;
    float* ws  = (float*)d_ws;

    unsigned short* w1t_en = (unsigned short*)(ws + W1T_EN);
    unsigned short* w1t_cn = (unsigned short*)(ws + W1T_CN);
    unsigned short* w2t_en = (unsigned short*)(ws + W2T_EN);
    unsigned short* w2t_cn = (unsigned short*)(ws + W2T_CN);
    unsigned short* h1b_en = (unsigned short*)(ws + H1B_EN);
    unsigned short* h1b_cn = (unsigned short*)(ws + H1B_CN);
    unsigned short* xb_en  = (unsigned short*)(ws + XB_EN);
    unsigned short* xb_cn  = (unsigned short*)(ws + XB_CN);
    unsigned short* wep_en = (unsigned short*)(ws + WEP_EN);
    unsigned short* wep_cn = (unsigned short*)(ws + WEP_CN);
    unsigned short* tep    = (unsigned short*)(ws + TEP);
    unsigned short* bt_en  = (unsigned short*)(ws + BT_EN);
    unsigned short* bt_cn  = (unsigned short*)(ws + BT_CN);
    unsigned short* thp_en = (unsigned short*)(ws + THP_EN);
    unsigned short* thp_cn = (unsigned short*)(ws + THP_CN);

    hipMemsetAsync(d_ws, 0, (size_t)ZERO_FLOATS * sizeof(float), stream);

    // ---- phase 1: encoders (x pre-cast to padded bf16; GEMM1 async-staged) ----
    cast_pad_bf16_kernel<<<dim3(15, 512), 256, 0, stream>>>(x_en, xb_en, VEN, VENK);
    cast_pad_bf16_kernel<<<dim3(10, 512), 256, 0, stream>>>(x_cn, xb_cn, VCN, VCNK);

    transpose_cast_kernel<<<dim3(940, 16), 256, 0, stream>>>(W1_en, w1t_en, VEN, HID, VENK);
    transpose_cast_kernel<<<dim3(628, 16), 256, 0, stream>>>(W1_cn, w1t_cn, VCN, HID, VCNK);
    transpose_cast_kernel<<<dim3(16, 16), 256, 0, stream>>>(W2_en, w2t_en, HID, HID, HID);
    transpose_cast_kernel<<<dim3(16, 16), 256, 0, stream>>>(W2_cn, w2t_cn, HID, HID, HID);

    gemm1_async<<<dim3(4, 4, 47), 256, 0, stream>>>(xb_en, w1t_en, ws + WS_H1_EN,
        HID, VENK, VENK, 640, VENK);
    gemm1_async<<<dim3(4, 4, 32), 256, 0, stream>>>(xb_cn, w1t_cn, ws + WS_H1_CN,
        HID, VCNK, VCNK, 640, VCNK);

    bias_softplus_bf16_kernel<<<1024, 256, 0, stream>>>(ws + WS_H1_EN, b1_en, h1b_en, 262144);
    bias_softplus_bf16_kernel<<<1024, 256, 0, stream>>>(ws + WS_H1_CN, b1_cn, h1b_cn, 262144);

    mfma_gemm_nt<0, 0><<<dim3(4, 4, 16), 256, 0, stream>>>(h1b_en, w2t_en, ws + WS_H2_EN,
        BATCH, HID, HID, HID, HID, 32, 0, nullptr, nullptr);
    mfma_gemm_nt<0, 0><<<dim3(4, 4, 16), 256, 0, stream>>>(h1b_cn, w2t_cn, ws + WS_H2_CN,
        BATCH, HID, HID, HID, HID, 32, 0, nullptr, nullptr);

    bias_softplus_f32_kernel<<<1024, 256, 0, stream>>>(ws + WS_H2_EN, b2_en, 262144);
    bias_softplus_f32_kernel<<<1024, 256, 0, stream>>>(ws + WS_H2_CN, b2_cn, 262144);

    encoder_head_kernel<<<BATCH, 128, 0, stream>>>(ws + WS_H2_EN, Wmu_en, bmu_en, Wlv_en, blv_en,
                                                   eps_en, out + OUT_THETA_EN, ws + WS_SCAL + 0);
    encoder_head_kernel<<<BATCH, 128, 0, stream>>>(ws + WS_H2_CN, Wmu_cn, bmu_cn, Wlv_cn, blv_cn,
                                                   eps_cn, out + OUT_THETA_CN, ws + WS_SCAL + 1);

    // ---- phase 2: beta path (BIG region reused; all phase-1 reads of xb complete) ----
    padcast_sqnorm_kernel<<<VENP, 64, 0, stream>>>(we_en, wep_en, ws + WN2_EN, VEN);
    padcast_sqnorm_kernel<<<VCNP, 64, 0, stream>>>(we_cn, wep_cn, ws + WN2_CN, VCN);
    padcast_sqnorm_kernel<<<128, 64, 0, stream>>>(te, tep, ws + TN2, KT);

    mfma_gemm_nt<2, 0><<<dim3(235, 1, 1), 256, 0, stream>>>(wep_en, tep, out + OUT_BETA_EN,
        VENP, 128, KDP, KDP, KDP, KDP, VEN, ws + WN2_EN, ws + TN2);
    mfma_gemm_nt<2, 0><<<dim3(157, 1, 1), 256, 0, stream>>>(wep_cn, tep, out + OUT_BETA_CN,
        VCNP, 128, KDP, KDP, KDP, KDP, VCN, ws + WN2_CN, ws + TN2);

    colsum_kernel<<<KT, 256, 0, stream>>>(out + OUT_BETA_EN, ws + WS_COLSUM_EN, VEN);
    colsum_kernel<<<KT, 256, 0, stream>>>(out + OUT_BETA_CN, ws + WS_COLSUM_CN, VCN);

    normbeta_bt_kernel<<<VENP / 64, 256, 0, stream>>>(out + OUT_BETA_EN, ws + WS_COLSUM_EN, bt_en, VEN);
    normbeta_bt_kernel<<<VCNP / 64, 256, 0, stream>>>(out + OUT_BETA_CN, ws + WS_COLSUM_CN, bt_cn, VCN);

    // ---- recon via MFMA ----
    theta_pad_kernel<<<256, 256, 0, stream>>>(out + OUT_THETA_EN, thp_en);
    theta_pad_kernel<<<256, 256, 0, stream>>>(out + OUT_THETA_CN, thp_cn);

    recon_mfma_kernel<<<dim3(VENP / 128, 4), 256, 0, stream>>>(bt_en, thp_en, x_en, VEN, ws + WS_ROWS_EN);
    recon_mfma_kernel<<<dim3(VCNP / 128, 4), 256, 0, stream>>>(bt_cn, thp_cn, x_cn, VCN, ws + WS_ROWS_CN);
    recon_finalize_kernel<<<2, 256, 0, stream>>>(ws + WS_ROWS_EN, ws + WS_ROWS_CN, ws + WS_SCAL);

    // ---- contrastive ----
    contrast_prep_kernel<<<BATCH, 128, 0, stream>>>(out + OUT_THETA_EN, out + OUT_THETA_CN, ws + WS_TNBUF);
    contrast_main_kernel<<<BATCH, 256, 0, stream>>>(ws + WS_TNBUF, cid, ws + WS_SCAL);

    // ---- alignment ----
    norm_rows_kernel<<<KT, 64, 0, stream>>>(te, ws + WS_TNT, DIM);
    ctopic_kernel<<<KT, 128, 0, stream>>>(ws + WS_TNT, ws + WS_CTOP);
    sinkhorn_kernel<<<1, 128, 0, stream>>>(ws + WS_CTOP, ws + WS_SCAL);

    final_combine_kernel<<<1, 64, 0, stream>>>(ws + WS_SCAL, out);
}

// Round 4
// 887.666 us; speedup vs baseline: 1.0074x; 1.0039x over previous
//
#include <hip/hip_runtime.h>
#include <math.h>

#define BATCH 512
#define VEN 30000
#define VCN 20000
#define KT 100
#define HID 512
#define DIM 300
#define VENP 30080   // padded to 128
#define VCNP 20096
#define KDP 320      // DIM padded to mult of 64
#define VENK 30080   // K padded to mult of 64 for gemm1
#define VCNK 20096

typedef float f32x4 __attribute__((ext_vector_type(4)));
typedef short bf16x8 __attribute__((ext_vector_type(8)));
typedef unsigned short u16x8 __attribute__((ext_vector_type(8)));
typedef unsigned int u32;

// ---------------- workspace layout (float offsets) ----------------
#define WS_H1_EN   0
#define WS_H2_EN   (WS_H1_EN + 262144)
#define WS_H1_CN   (WS_H2_EN + 262144)
#define WS_H2_CN   (WS_H1_CN + 262144)
#define WS_ROWS_EN (WS_H2_CN + 262144)
#define WS_ROWS_CN (WS_ROWS_EN + 1536)
#define WS_SCAL    (WS_ROWS_CN + 1536)
#define ZERO_FLOATS (WS_SCAL + 64)
// BIG aliased region: phase 1 = padded bf16 copies of x; phase 2 = WEP/TEP + BT/THP
#define WS_BIG     ZERO_FLOATS
#define XB_EN      WS_BIG                       // 512*30080 u16 = 7,700,480 f
#define XB_CN      (WS_BIG + 7700480)           // 512*20096 u16 = 5,144,576 f
#define WEP_EN     WS_BIG                       // 4,812,800 f
#define WEP_CN     (WS_BIG + 4812800)           // 3,215,360 f
#define TEP        (WS_BIG + 4812800 + 3215360) // 20,480 f
#define BT_EN      (WS_BIG + 8048640)           // 30080*128 u16 = 1,925,120 f
#define BT_CN      (BT_EN + 1925120)            // 20096*128 u16 = 1,286,144 f
#define THP_EN     (BT_CN + 1286144)            // 512*128 u16 = 32,768 f
#define THP_CN     (THP_EN + 32768)
#define AFTER_BIG  (WS_BIG + 12845056)
#define W1T_EN     AFTER_BIG                    // 512*30080 u16 = 7,700,480 f
#define W1T_CN     (W1T_EN + 7700480)           // 512*20096 u16 = 5,144,576 f
#define W2T_EN     (W1T_CN + 5144576)
#define W2T_CN     (W2T_EN + 131072)
#define H1B_EN     (W2T_CN + 131072)
#define H1B_CN     (H1B_EN + 131072)
#define WN2_EN     (H1B_CN + 131072)            // 30080
#define WN2_CN     (WN2_EN + 30080)             // 20096
#define TN2        (WN2_CN + 20096)             // 128
#define WS_TNBUF   (TN2 + 128)                  // 51200
#define WS_TNT     (WS_TNBUF + 51200)           // 30000
#define WS_CTOP    (WS_TNT + 30000)             // 10000
#define WS_COLSUM_EN (WS_CTOP + 10000)          // 128
#define WS_COLSUM_CN (WS_COLSUM_EN + 128)

// ---------------- output layout (float offsets) ----------------
#define OUT_THETA_EN 5
#define OUT_THETA_CN (OUT_THETA_EN + 51200)
#define OUT_BETA_EN  (OUT_THETA_CN + 51200)
#define OUT_BETA_CN  (OUT_BETA_EN + 3000000)

__device__ __forceinline__ float waveReduceSum(float v) {
    #pragma unroll
    for (int o = 32; o > 0; o >>= 1) v += __shfl_down(v, o);
    return v;
}

__device__ __forceinline__ unsigned short f2bf(float f) {
    unsigned int u = __float_as_uint(f);
    u = (u + 0x7FFFu + ((u >> 16) & 1u)) >> 16;   // RNE
    return (unsigned short)u;
}

// async global->LDS, 16 B per lane: LDS dest = wave-uniform base + lane*16
__device__ __forceinline__ void gl2lds16(const unsigned short* g, unsigned short* l) {
    __builtin_amdgcn_global_load_lds(
        (const __attribute__((address_space(1))) u32*)g,
        (__attribute__((address_space(3))) u32*)l, 16, 0, 0);
}

// f32 -> bf16 cast with column zero-padding: dst [rows][colsPad]
__global__ __launch_bounds__(256)
void cast_pad_bf16_kernel(const float* __restrict__ src, unsigned short* __restrict__ dst,
                          int cols, int colsPad)
{
    int row = blockIdx.y;
    int col = (blockIdx.x * 256 + threadIdx.x) * 8;
    if (col >= colsPad) return;
    u16x8 o = {0,0,0,0,0,0,0,0};
    if (col < cols) {   // cols % 8 == 0 -> chunk fully valid
        float4 a = *(const float4*)&src[(size_t)row * cols + col];
        float4 b = *(const float4*)&src[(size_t)row * cols + col + 4];
        o = (u16x8){ f2bf(a.x), f2bf(a.y), f2bf(a.z), f2bf(a.w),
                     f2bf(b.x), f2bf(b.y), f2bf(b.z), f2bf(b.w) };
    }
    *(u16x8*)&dst[(size_t)row * colsPad + col] = o;
}

// ============ async-staged bf16 MFMA NT GEMM ============
// A [*][ldA] bf16 zero-padded (ldA mult of 64); B [*][ldB] likewise.
// Tile 128x128, BK=64, 256 threads (4 waves). LDS linear [128][64] with chunk
// XOR-swizzle c ^= (row&7) applied on the GLOBAL source address and on ds_read.
// MODE 0: C[m*N+n] += acc via atomicAdd (split-K, C pre-zeroed).
// MODE 1: C[m*N+n] = acc direct store (z=1, exact tiling).
// MODE 2: beta epilogue: C[n*Mreal+m] = exp(-sqrt(an2[m]+bn2[n]-2*acc)).
template <int MODE>
__global__ __launch_bounds__(256)
void gemm_async(const unsigned short* __restrict__ A, const unsigned short* __restrict__ B,
                float* __restrict__ C, int N, int ldA, int ldB, int chunkK, int K,
                int Mreal, const float* __restrict__ an2, const float* __restrict__ bn2)
{
    __shared__ __align__(16) unsigned short As[128 * 64];
    __shared__ __align__(16) unsigned short Bs[128 * 64];
    const int tid = threadIdx.x;
    const int m0 = blockIdx.x * 128, n0 = blockIdx.y * 128;
    const int kStart = blockIdx.z * chunkK;
    const int kEnd = min(kStart + chunkK, K);   // multiples of 64

    const int wave = tid >> 6, lane = tid & 63;
    const int wm = (wave & 1) * 64, wn = (wave >> 1) * 64;
    const int l15 = lane & 15, quad = lane >> 4;

    // staging geometry: each wave-instruction covers 8 rows x 64 elems (1 KB)
    const int rl = lane >> 3;                 // row within 8-row group
    const int cs = (lane & 7) ^ rl;           // swizzled source chunk (8 elems)

    f32x4 acc[4][4];
    #pragma unroll
    for (int i = 0; i < 4; ++i)
        #pragma unroll
        for (int j = 0; j < 4; ++j)
            acc[i][j] = (f32x4){0.f, 0.f, 0.f, 0.f};

    for (int k0 = kStart; k0 < kEnd; k0 += 64) {
        #pragma unroll
        for (int j = 0; j < 4; ++j) {
            int seg = wave * 4 + j;                       // 0..15
            int r = seg * 8 + rl;                         // 0..127
            gl2lds16(A + (size_t)(m0 + r) * ldA + k0 + cs * 8, &As[seg * 512]);
            gl2lds16(B + (size_t)(n0 + r) * ldB + k0 + cs * 8, &Bs[seg * 512]);
        }
        asm volatile("s_waitcnt vmcnt(0)" ::: "memory");
        __syncthreads();

        #pragma unroll
        for (int kh = 0; kh < 2; ++kh) {
            bf16x8 af[4], bfr[4];
            #pragma unroll
            for (int mi = 0; mi < 4; ++mi) {
                int r = wm + mi * 16 + l15;
                af[mi] = *(const bf16x8*)&As[r * 64 + (((kh << 2) | quad) ^ (r & 7)) * 8];
            }
            #pragma unroll
            for (int ni = 0; ni < 4; ++ni) {
                int r = wn + ni * 16 + l15;
                bfr[ni] = *(const bf16x8*)&Bs[r * 64 + (((kh << 2) | quad) ^ (r & 7)) * 8];
            }
            #pragma unroll
            for (int mi = 0; mi < 4; ++mi)
                #pragma unroll
                for (int ni = 0; ni < 4; ++ni)
                    acc[mi][ni] = __builtin_amdgcn_mfma_f32_16x16x32_bf16(af[mi], bfr[ni], acc[mi][ni], 0, 0, 0);
        }
        __syncthreads();
    }

    #pragma unroll
    for (int mi = 0; mi < 4; ++mi)
        #pragma unroll
        for (int ni = 0; ni < 4; ++ni)
            #pragma unroll
            for (int i = 0; i < 4; ++i) {
                int m = m0 + wm + mi * 16 + quad * 4 + i;
                int n = n0 + wn + ni * 16 + l15;
                if (MODE == 0) {
                    atomicAdd(&C[(size_t)m * N + n], acc[mi][ni][i]);
                } else if (MODE == 1) {
                    C[(size_t)m * N + n] = acc[mi][ni][i];
                } else {
                    if (m < Mreal && n < KT) {
                        float sq = an2[m] + bn2[n] - 2.f * acc[mi][ni][i];
                        C[(size_t)n * Mreal + m] = __expf(-sqrtf(fmaxf(sq, 0.f)));
                    }
                }
            }
}

// ============ recon MFMA (async-staged): r = bt[V][128] x thp[B][128]; fused loss ============
__global__ __launch_bounds__(256)
void recon_mfma_kernel(const unsigned short* __restrict__ A, const unsigned short* __restrict__ B,
                       const float* __restrict__ x, int V, float* __restrict__ rows)
{
    __shared__ __align__(16) unsigned short As[128 * 64];
    __shared__ __align__(16) unsigned short Bs[128 * 64];
    const int tid = threadIdx.x;
    const int m0 = blockIdx.x * 128, n0 = blockIdx.y * 128;
    const int wave = tid >> 6, lane = tid & 63;
    const int wm = (wave & 1) * 64, wn = (wave >> 1) * 64;
    const int l15 = lane & 15, quad = lane >> 4;
    const int rl = lane >> 3;
    const int cs = (lane & 7) ^ rl;

    f32x4 acc[4][4];
    #pragma unroll
    for (int i = 0; i < 4; ++i)
        #pragma unroll
        for (int j = 0; j < 4; ++j)
            acc[i][j] = (f32x4){0.f, 0.f, 0.f, 0.f};

    for (int k0 = 0; k0 < 128; k0 += 64) {
        #pragma unroll
        for (int j = 0; j < 4; ++j) {
            int seg = wave * 4 + j;
            int r = seg * 8 + rl;
            gl2lds16(A + (size_t)(m0 + r) * 128 + k0 + cs * 8, &As[seg * 512]);
            gl2lds16(B + (size_t)(n0 + r) * 128 + k0 + cs * 8, &Bs[seg * 512]);
        }
        asm volatile("s_waitcnt vmcnt(0)" ::: "memory");
        __syncthreads();

        #pragma unroll
        for (int kh = 0; kh < 2; ++kh) {
            bf16x8 af[4], bfr[4];
            #pragma unroll
            for (int mi = 0; mi < 4; ++mi) {
                int r = wm + mi * 16 + l15;
                af[mi] = *(const bf16x8*)&As[r * 64 + (((kh << 2) | quad) ^ (r & 7)) * 8];
            }
            #pragma unroll
            for (int ni = 0; ni < 4; ++ni) {
                int r = wn + ni * 16 + l15;
                bfr[ni] = *(const bf16x8*)&Bs[r * 64 + (((kh << 2) | quad) ^ (r & 7)) * 8];
            }
            #pragma unroll
            for (int mi = 0; mi < 4; ++mi)
                #pragma unroll
                for (int ni = 0; ni < 4; ++ni)
                    acc[mi][ni] = __builtin_amdgcn_mfma_f32_16x16x32_bf16(af[mi], bfr[ni], acc[mi][ni], 0, 0, 0);
        }
        __syncthreads();
    }

    #pragma unroll
    for (int ni = 0; ni < 4; ++ni) {
        int b = n0 + wn + ni * 16 + l15;
        float tse = 0.f, tsxr = 0.f, tsx = 0.f;
        #pragma unroll
        for (int mi = 0; mi < 4; ++mi) {
            int v0 = m0 + wm + mi * 16 + quad * 4;
            if (v0 + 3 < V) {
                float4 xv = *(const float4*)&x[(size_t)b * V + v0];
                float xa[4] = {xv.x, xv.y, xv.z, xv.w};
                #pragma unroll
                for (int i = 0; i < 4; ++i) {
                    float r = acc[mi][ni][i];
                    tse += __expf(r);
                    tsxr += xa[i] * r;
                    tsx  += xa[i];
                }
            } else {
                #pragma unroll
                for (int i = 0; i < 4; ++i) {
                    int v = v0 + i;
                    if (v < V) {
                        float xv1 = x[(size_t)b * V + v];
                        float r = acc[mi][ni][i];
                        tse += __expf(r); tsxr += xv1 * r; tsx += xv1;
                    }
                }
            }
        }
        tse  += __shfl_xor(tse, 16);  tse  += __shfl_xor(tse, 32);
        tsxr += __shfl_xor(tsxr, 16); tsxr += __shfl_xor(tsxr, 32);
        tsx  += __shfl_xor(tsx, 16);  tsx  += __shfl_xor(tsx, 32);
        if (quad == 0) {
            atomicAdd(&rows[b], tse);
            atomicAdd(&rows[512 + b], tsxr);
            atomicAdd(&rows[1024 + b], tsx);
        }
    }
}

// ================= cast / transpose kernels =================
__global__ __launch_bounds__(256)
void transpose_cast_kernel(const float* __restrict__ src, unsigned short* __restrict__ dst,
                           int K, int N, int Kp)
{
    __shared__ float tile[32][33];
    int kb = blockIdx.x * 32, nb = blockIdx.y * 32;
    int tx = threadIdx.x & 31, ty4 = threadIdx.x >> 5;
    #pragma unroll
    for (int j = 0; j < 4; ++j) {
        int k = kb + ty4 * 4 + j;
        tile[ty4 * 4 + j][tx] = (k < K) ? src[(size_t)k * N + nb + tx] : 0.f;
    }
    __syncthreads();
    #pragma unroll
    for (int j = 0; j < 4; ++j) {
        int n = nb + ty4 * 4 + j;
        int k = kb + tx;
        if (k < Kp) dst[(size_t)n * Kp + k] = f2bf(tile[tx][ty4 * 4 + j]);
    }
}

// fused: word_emb [V][300] f32 -> [Vp][320] bf16 zero-padded + row sqnorm
__global__ void padcast_sqnorm_kernel(const float* __restrict__ src, unsigned short* __restrict__ dst,
                                      float* __restrict__ n2, int V)
{
    int m = blockIdx.x, tid = threadIdx.x;   // 64 threads
    float sq = 0.f;
    #pragma unroll
    for (int j = 0; j < 5; ++j) {
        int k = tid + j * 64;
        float v = (m < V && k < DIM) ? src[(size_t)m * DIM + k] : 0.f;
        dst[(size_t)m * KDP + k] = f2bf(v);
        sq += v * v;
    }
    sq = waveReduceSum(sq);
    if (tid == 0) n2[m] = sq;
}

// fused: normalize beta in place (f32, out buffer) + build bt [Vp][128] bf16
__global__ __launch_bounds__(256)
void normbeta_bt_kernel(float* __restrict__ beta, const float* __restrict__ cs,
                        unsigned short* __restrict__ bt, int V)
{
    int v = blockIdx.x * 64 + (threadIdx.x & 63);
    int kq = threadIdx.x >> 6;   // 0..3
    unsigned short tmp[32];
    #pragma unroll
    for (int j = 0; j < 32; ++j) {
        int k = kq * 32 + j;
        float val = 0.f;
        if (k < KT && v < V) {
            val = beta[(size_t)k * V + v] * (1.0f / cs[k]);
            beta[(size_t)k * V + v] = val;
        }
        tmp[j] = f2bf(val);
    }
    #pragma unroll
    for (int q = 0; q < 4; ++q)
        *(u16x8*)&bt[(size_t)v * 128 + kq * 32 + q * 8] = *(u16x8*)&tmp[q * 8];
}

__global__ void theta_pad_kernel(const float* __restrict__ theta, unsigned short* __restrict__ thp)
{
    int idx = blockIdx.x * 256 + threadIdx.x;  // 65536 total
    int b = idx >> 7, k = idx & 127;
    thp[idx] = f2bf(k < KT ? theta[b * KT + k] : 0.f);
}

__global__ __launch_bounds__(256)
void colsum_kernel(const float* __restrict__ bta, float* __restrict__ cs, int V)
{
    int k = blockIdx.x, tid = threadIdx.x;
    float s = 0.f;
    for (int v = tid; v < V; v += 256) s += bta[(size_t)k * V + v];
    s = waveReduceSum(s);
    __shared__ float cw[4];
    if ((tid & 63) == 0) cw[tid >> 6] = s;
    __syncthreads();
    if (tid == 0) cs[k] = cw[0] + cw[1] + cw[2] + cw[3];
}

__global__ void bias_softplus_bf16_kernel(const float* __restrict__ src, const float* __restrict__ b,
                                          unsigned short* __restrict__ dst, int n)
{
    int i = blockIdx.x * 256 + threadIdx.x;
    if (i < n) {
        float x = src[i] + b[i & (HID - 1)];
        float sp = fmaxf(x, 0.f) + log1pf(__expf(-fabsf(x)));
        dst[i] = f2bf(sp);
    }
}

__global__ void bias_softplus_f32_kernel(float* __restrict__ y, const float* __restrict__ b, int n)
{
    int i = blockIdx.x * 256 + threadIdx.x;
    if (i < n) {
        float x = y[i] + b[i & (HID - 1)];
        y[i] = fmaxf(x, 0.f) + log1pf(__expf(-fabsf(x)));
    }
}

// ================= encoder head =================
__global__ __launch_bounds__(128)
void encoder_head_kernel(const float* __restrict__ h2, const float* __restrict__ Wmu,
                         const float* __restrict__ bmu, const float* __restrict__ Wlv,
                         const float* __restrict__ blv, const float* __restrict__ eps,
                         float* __restrict__ theta_out, float* __restrict__ kl_accum)
{
    int i = blockIdx.x, tid = threadIdx.x;
    __shared__ float hrow[HID];
    __shared__ float sred[128];
    #pragma unroll
    for (int j = 0; j < 4; ++j) hrow[tid + 128 * j] = h2[i * HID + tid + 128 * j];
    __syncthreads();
    float mu = 0.f, lv = 0.f;
    if (tid < KT) {
        #pragma unroll 8
        for (int h = 0; h < HID; ++h) {
            float hv = hrow[h];
            mu += hv * Wmu[h * KT + tid];
            lv += hv * Wlv[h * KT + tid];
        }
        mu += bmu[tid]; lv += blv[tid];
    }
    float z = (tid < KT) ? (mu + eps[i * KT + tid] * __expf(0.5f * lv)) : -3.0e38f;
    sred[tid] = z; __syncthreads();
    for (int s = 64; s > 0; s >>= 1) { if (tid < s) sred[tid] = fmaxf(sred[tid], sred[tid + s]); __syncthreads(); }
    float zmax = sred[0]; __syncthreads();
    float e = (tid < KT) ? __expf(z - zmax) : 0.f;
    sred[tid] = e; __syncthreads();
    for (int s = 64; s > 0; s >>= 1) { if (tid < s) sred[tid] += sred[tid + s]; __syncthreads(); }
    float esum = sred[0]; __syncthreads();
    if (tid < KT) theta_out[i * KT + tid] = e / esum;
    float kterm = (tid < KT) ? 0.5f * (__expf(lv) + mu * mu - 1.f - lv) : 0.f;
    sred[tid] = kterm; __syncthreads();
    for (int s = 64; s > 0; s >>= 1) { if (tid < s) sred[tid] += sred[tid + s]; __syncthreads(); }
    if (tid == 0) atomicAdd(kl_accum, sred[0]);
}

__global__ __launch_bounds__(256)
void recon_finalize_kernel(const float* __restrict__ rows_en, const float* __restrict__ rows_cn,
                           float* __restrict__ scal)
{
    const float* rows = (blockIdx.x == 0) ? rows_en : rows_cn;
    int tid = threadIdx.x;
    float s = 0.f;
    for (int r = tid; r < 512; r += 256) {
        float se = rows[r], sxr = rows[512 + r], sx = rows[1024 + r];
        s += __logf(se) * sx - sxr;
    }
    s = waveReduceSum(s);
    __shared__ float cw[4];
    if ((tid & 63) == 0) cw[tid >> 6] = s;
    __syncthreads();
    if (tid == 0) scal[5 + blockIdx.x] = cw[0] + cw[1] + cw[2] + cw[3];
}

// ================= contrastive =================
__global__ __launch_bounds__(128)
void contrast_prep_kernel(const float* __restrict__ theta_en, const float* __restrict__ theta_cn,
                          float* __restrict__ tn)
{
    int i = blockIdx.x, tid = threadIdx.x;
    const float* src = ((i & 1) == 0) ? theta_en : theta_cn;
    float val = (tid < KT) ? src[i * KT + tid] : 0.f;
    __shared__ float sred[128];
    sred[tid] = val * val; __syncthreads();
    for (int s = 64; s > 0; s >>= 1) { if (tid < s) sred[tid] += sred[tid + s]; __syncthreads(); }
    float inv = 1.0f / fmaxf(sqrtf(sred[0]), 1e-8f);
    if (tid < KT) tn[i * KT + tid] = val * inv;
}

__global__ __launch_bounds__(256)
void contrast_main_kernel(const float* __restrict__ tn, const int* __restrict__ cid,
                          float* __restrict__ scal)
{
    int i = blockIdx.x, tid = threadIdx.x;
    __shared__ __align__(16) float ti[KT];
    if (tid < KT) ti[tid] = tn[i * KT + tid];
    __syncthreads();
    int ci = cid[i];
    bool vi = ci > 0;
    float pos = 0.f, neg = 0.f, pcnt = 0.f;
    for (int j = tid; j < 512; j += 256) {
        if (j == i) continue;
        float s = 0.f;
        const float4* tj = reinterpret_cast<const float4*>(&tn[j * KT]);
        #pragma unroll
        for (int q = 0; q < 25; ++q) {
            float4 t4 = tj[q];
            s += ti[4 * q] * t4.x + ti[4 * q + 1] * t4.y + ti[4 * q + 2] * t4.z + ti[4 * q + 3] * t4.w;
        }
        float E = __expf(s);
        neg += E;
        if (vi && cid[j] == ci) { pos += E; pcnt += 1.f; }
    }
    pos = waveReduceSum(pos); neg = waveReduceSum(neg); pcnt = waveReduceSum(pcnt);
    __shared__ float cw[3][4];
    int w = tid >> 6;
    if ((tid & 63) == 0) { cw[0][w] = pos; cw[1][w] = neg; cw[2][w] = pcnt; }
    __syncthreads();
    if (tid == 0) {
        float P = 0.f, N = 0.f, PC = 0.f;
        for (int q = 0; q < 4; ++q) { P += cw[0][q]; N += cw[1][q]; PC += cw[2][q]; }
        if (vi && PC > 0.f) {
            atomicAdd(&scal[2], -__logf(P / (P + N + 1e-8f)));
            atomicAdd(&scal[3], 1.0f);
        }
    }
}

// ================= alignment / sinkhorn =================
__global__ void norm_rows_kernel(const float* __restrict__ A, float* __restrict__ out, int cols)
{
    int r = blockIdx.x, tid = threadIdx.x;
    float s = 0.f;
    for (int d = tid; d < cols; d += 64) { float a = A[r * cols + d]; s += a * a; }
    s = waveReduceSum(s);
    s = __shfl(s, 0);
    float inv = 1.0f / fmaxf(sqrtf(s), 1e-8f);
    for (int d = tid; d < cols; d += 64) out[r * cols + d] = A[r * cols + d] * inv;
}

__global__ __launch_bounds__(128)
void ctopic_kernel(const float* __restrict__ tnt, float* __restrict__ C)
{
    int i = blockIdx.x, tid = threadIdx.x;
    __shared__ float ti[DIM];
    for (int d = tid; d < DIM; d += 128) ti[d] = tnt[i * DIM + d];
    __syncthreads();
    for (int j = tid; j < KT; j += 128) {
        float s = 0.f;
        for (int d = 0; d < DIM; ++d) s += ti[d] * tnt[j * DIM + d];
        C[i * KT + j] = 1.0f - s;
    }
}

// role-split sinkhorn: threads 0..99 own K-rows (kk in VGPRs), threads 128..227
// own K-cols (kk in VGPRs). ~125 VGPR/thread -> no scratch (old version spilled
// kr[100]+kc[100] to scratch: 70us). C reconstructed as -0.1*ln(K) for the loss.
__global__ __launch_bounds__(256, 1)
void sinkhorn_kernel(const float* __restrict__ C, float* __restrict__ scal)
{
    __shared__ __align__(16) float ub[128], vb[128];
    __shared__ float cw[4];
    const int tid = threadIdx.x;
    const bool gA = (tid < 100);
    const bool gB = (tid >= 128 && tid < 228);
    const int rc = gA ? tid : (tid - 128);

    float kk[100];
    if (gA) {
        #pragma unroll
        for (int j = 0; j < 100; ++j) kk[j] = __expf(-10.f * C[rc * 100 + j]);
    } else if (gB) {
        #pragma unroll
        for (int j = 0; j < 100; ++j) kk[j] = __expf(-10.f * C[j * 100 + rc]);
    }
    if (tid < 128) { ub[tid] = 1.f; vb[tid] = 1.f; }
    __syncthreads();

    for (int it = 0; it < 50; ++it) {
        if (gA) {
            float s = 0.f;
            #pragma unroll
            for (int q = 0; q < 25; ++q) {
                float4 v4 = *(const float4*)&vb[q * 4];
                s += kk[q*4]*v4.x + kk[q*4+1]*v4.y + kk[q*4+2]*v4.z + kk[q*4+3]*v4.w;
            }
            ub[rc] = 0.01f / (s + 1e-8f);
        }
        __syncthreads();
        if (gB) {
            float s = 0.f;
            #pragma unroll
            for (int q = 0; q < 25; ++q) {
                float4 u4 = *(const float4*)&ub[q * 4];
                s += kk[q*4]*u4.x + kk[q*4+1]*u4.y + kk[q*4+2]*u4.z + kk[q*4+3]*u4.w;
            }
            vb[rc] = 0.01f / (s + 1e-8f);
        }
        __syncthreads();
    }

    // loss = sum_ij u_i K_ij C_ij v_j ; C_ij = -0.1*ln(K_ij)
    float part = 0.f;
    if (gA) {
        float u = ub[rc];
        #pragma unroll
        for (int j = 0; j < 100; ++j) {
            float k = kk[j];
            part += u * k * vb[j] * (-0.1f * __logf(k));
        }
    }
    part = waveReduceSum(part);
    if ((tid & 63) == 0) cw[tid >> 6] = part;
    __syncthreads();
    if (tid == 0) scal[4] = cw[0] + cw[1] + cw[2] + cw[3];
}

__global__ void final_combine_kernel(const float* __restrict__ scal, float* __restrict__ out)
{
    if (threadIdx.x == 0 && blockIdx.x == 0) {
        const float invB = 1.0f / 512.0f;
        float tm_en = scal[5] * invB + scal[0] * invB;
        float tm_cn = scal[6] * invB + scal[1] * invB;
        float contrast = scal[2] / (scal[3] + 1e-8f);
        float align = scal[4];
        out[0] = tm_en + tm_cn + contrast + align;
        out[1] = tm_en;
        out[2] = tm_cn;
        out[3] = contrast;
        out[4] = align;
    }
}

// ================= launch =================
extern "C" void kernel_launch(void* const* d_in, const int* in_sizes, int n_in,
                              void* d_out_v, int out_size, void* d_ws, size_t ws_size,
                              hipStream_t stream)
{
    const float* x_en   = (const float*)d_in[0];
    const float* x_cn   = (const float*)d_in[1];
    const int*   cid    = (const int*)  d_in[2];
    const float* eps_en = (const float*)d_in[3];
    const float* eps_cn = (const float*)d_in[4];
    const float* W1_en  = (const float*)d_in[5];
    const float* b1_en  = (const float*)d_in[6];
    const float* W2_en  = (const float*)d_in[7];
    const float* b2_en  = (const float*)d_in[8];
    const float* Wmu_en = (const float*)d_in[9];
    const float* bmu_en = (const float*)d_in[10];
    const float* Wlv_en = (const float*)d_in[11];
    const float* blv_en = (const float*)d_in[12];
    const float* W1_cn  = (const float*)d_in[13];
    const float* b1_cn  = (const float*)d_in[14];
    const float* W2_cn  = (const float*)d_in[15];
    const float* b2_cn  = (const float*)d_in[16];
    const float* Wmu_cn = (const float*)d_in[17];
    const float* bmu_cn = (const float*)d_in[18];
    const float* Wlv_cn = (const float*)d_in[19];
    const float* blv_cn = (const float*)d_in[20];
    const float* we_en  = (const float*)d_in[21];
    const float* we_cn  = (const float*)d_in[22];
    const float* te     = (const float*)d_in[23];
    float* out = (float*)d_out_v;
    float* ws  = (float*)d_ws;

    unsigned short* w1t_en = (unsigned short*)(ws + W1T_EN);
    unsigned short* w1t_cn = (unsigned short*)(ws + W1T_CN);
    unsigned short* w2t_en = (unsigned short*)(ws + W2T_EN);
    unsigned short* w2t_cn = (unsigned short*)(ws + W2T_CN);
    unsigned short* h1b_en = (unsigned short*)(ws + H1B_EN);
    unsigned short* h1b_cn = (unsigned short*)(ws + H1B_CN);
    unsigned short* xb_en  = (unsigned short*)(ws + XB_EN);
    unsigned short* xb_cn  = (unsigned short*)(ws + XB_CN);
    unsigned short* wep_en = (unsigned short*)(ws + WEP_EN);
    unsigned short* wep_cn = (unsigned short*)(ws + WEP_CN);
    unsigned short* tep    = (unsigned short*)(ws + TEP);
    unsigned short* bt_en  = (unsigned short*)(ws + BT_EN);
    unsigned short* bt_cn  = (unsigned short*)(ws + BT_CN);
    unsigned short* thp_en = (unsigned short*)(ws + THP_EN);
    unsigned short* thp_cn = (unsigned short*)(ws + THP_CN);

    hipMemsetAsync(d_ws, 0, (size_t)ZERO_FLOATS * sizeof(float), stream);

    // ---- phase 1: encoders (x pre-cast to padded bf16; GEMMs async-staged) ----
    cast_pad_bf16_kernel<<<dim3(15, 512), 256, 0, stream>>>(x_en, xb_en, VEN, VENK);
    cast_pad_bf16_kernel<<<dim3(10, 512), 256, 0, stream>>>(x_cn, xb_cn, VCN, VCNK);

    transpose_cast_kernel<<<dim3(940, 16), 256, 0, stream>>>(W1_en, w1t_en, VEN, HID, VENK);
    transpose_cast_kernel<<<dim3(628, 16), 256, 0, stream>>>(W1_cn, w1t_cn, VCN, HID, VCNK);
    transpose_cast_kernel<<<dim3(16, 16), 256, 0, stream>>>(W2_en, w2t_en, HID, HID, HID);
    transpose_cast_kernel<<<dim3(16, 16), 256, 0, stream>>>(W2_cn, w2t_cn, HID, HID, HID);

    gemm_async<0><<<dim3(4, 4, 47), 256, 0, stream>>>(xb_en, w1t_en, ws + WS_H1_EN,
        HID, VENK, VENK, 640, VENK, 0, nullptr, nullptr);
    gemm_async<0><<<dim3(4, 4, 32), 256, 0, stream>>>(xb_cn, w1t_cn, ws + WS_H1_CN,
        HID, VCNK, VCNK, 640, VCNK, 0, nullptr, nullptr);

    bias_softplus_bf16_kernel<<<1024, 256, 0, stream>>>(ws + WS_H1_EN, b1_en, h1b_en, 262144);
    bias_softplus_bf16_kernel<<<1024, 256, 0, stream>>>(ws + WS_H1_CN, b1_cn, h1b_cn, 262144);

    // gemm2: full-K loop, direct store (no split-K atomics)
    gemm_async<1><<<dim3(4, 4, 1), 256, 0, stream>>>(h1b_en, w2t_en, ws + WS_H2_EN,
        HID, HID, HID, HID, HID, 0, nullptr, nullptr);
    gemm_async<1><<<dim3(4, 4, 1), 256, 0, stream>>>(h1b_cn, w2t_cn, ws + WS_H2_CN,
        HID, HID, HID, HID, HID, 0, nullptr, nullptr);

    bias_softplus_f32_kernel<<<1024, 256, 0, stream>>>(ws + WS_H2_EN, b2_en, 262144);
    bias_softplus_f32_kernel<<<1024, 256, 0, stream>>>(ws + WS_H2_CN, b2_cn, 262144);

    encoder_head_kernel<<<BATCH, 128, 0, stream>>>(ws + WS_H2_EN, Wmu_en, bmu_en, Wlv_en, blv_en,
                                                   eps_en, out + OUT_THETA_EN, ws + WS_SCAL + 0);
    encoder_head_kernel<<<BATCH, 128, 0, stream>>>(ws + WS_H2_CN, Wmu_cn, bmu_cn, Wlv_cn, blv_cn,
                                                   eps_cn, out + OUT_THETA_CN, ws + WS_SCAL + 1);

    // ---- phase 2: beta path (BIG region reused; all phase-1 reads of xb complete) ----
    padcast_sqnorm_kernel<<<VENP, 64, 0, stream>>>(we_en, wep_en, ws + WN2_EN, VEN);
    padcast_sqnorm_kernel<<<VCNP, 64, 0, stream>>>(we_cn, wep_cn, ws + WN2_CN, VCN);
    padcast_sqnorm_kernel<<<128, 64, 0, stream>>>(te, tep, ws + TN2, KT);

    gemm_async<2><<<dim3(235, 1, 1), 256, 0, stream>>>(wep_en, tep, out + OUT_BETA_EN,
        128, KDP, KDP, KDP, KDP, VEN, ws + WN2_EN, ws + TN2);
    gemm_async<2><<<dim3(157, 1, 1), 256, 0, stream>>>(wep_cn, tep, out + OUT_BETA_CN,
        128, KDP, KDP, KDP, KDP, VCN, ws + WN2_CN, ws + TN2);

    colsum_kernel<<<KT, 256, 0, stream>>>(out + OUT_BETA_EN, ws + WS_COLSUM_EN, VEN);
    colsum_kernel<<<KT, 256, 0, stream>>>(out + OUT_BETA_CN, ws + WS_COLSUM_CN, VCN);

    normbeta_bt_kernel<<<VENP / 64, 256, 0, stream>>>(out + OUT_BETA_EN, ws + WS_COLSUM_EN, bt_en, VEN);
    normbeta_bt_kernel<<<VCNP / 64, 256, 0, stream>>>(out + OUT_BETA_CN, ws + WS_COLSUM_CN, bt_cn, VCN);

    // ---- recon via MFMA ----
    theta_pad_kernel<<<256, 256, 0, stream>>>(out + OUT_THETA_EN, thp_en);
    theta_pad_kernel<<<256, 256, 0, stream>>>(out + OUT_THETA_CN, thp_cn);

    recon_mfma_kernel<<<dim3(VENP / 128, 4), 256, 0, stream>>>(bt_en, thp_en, x_en, VEN, ws + WS_ROWS_EN);
    recon_mfma_kernel<<<dim3(VCNP / 128, 4), 256, 0, stream>>>(bt_cn, thp_cn, x_cn, VCN, ws + WS_ROWS_CN);
    recon_finalize_kernel<<<2, 256, 0, stream>>>(ws + WS_ROWS_EN, ws + WS_ROWS_CN, ws + WS_SCAL);

    // ---- contrastive ----
    contrast_prep_kernel<<<BATCH, 128, 0, stream>>>(out + OUT_THETA_EN, out + OUT_THETA_CN, ws + WS_TNBUF);
    contrast_main_kernel<<<BATCH, 256, 0, stream>>>(ws + WS_TNBUF, cid, ws + WS_SCAL);

    // ---- alignment ----
    norm_rows_kernel<<<KT, 64, 0, stream>>>(te, ws + WS_TNT, DIM);
    ctopic_kernel<<<KT, 128, 0, stream>>>(ws + WS_TNT, ws + WS_CTOP);
    sinkhorn_kernel<<<1, 256, 0, stream>>>(ws + WS_CTOP, ws + WS_SCAL);

    final_combine_kernel<<<1, 64, 0, stream>>>(ws + WS_SCAL, out);
}

// Round 7
// 748.757 us; speedup vs baseline: 1.1943x; 1.1855x over previous
//
#include <hip/hip_runtime.h>
#include <math.h>

#define BATCH 512
#define VEN 30000
#define VCN 20000
#define KT 100
#define HID 512
#define DIM 300
#define VENP 30080   // padded to 128
#define VCNP 20096
#define KDP 320      // DIM padded to mult of 64
#define VENK 30080   // K padded to mult of 64 for gemm1
#define VCNK 20096

typedef float f32x4 __attribute__((ext_vector_type(4)));
typedef short bf16x8 __attribute__((ext_vector_type(8)));
typedef unsigned short u16x8 __attribute__((ext_vector_type(8)));
typedef unsigned int u32;

// ---------------- workspace layout (float offsets) ----------------
#define WS_H1_EN   0
#define WS_H2_EN   (WS_H1_EN + 262144)
#define WS_H1_CN   (WS_H2_EN + 262144)
#define WS_H2_CN   (WS_H1_CN + 262144)
#define WS_ROWS_EN (WS_H2_CN + 262144)
#define WS_ROWS_CN (WS_ROWS_EN + 1536)
#define WS_SCAL    (WS_ROWS_CN + 1536)
#define ZERO_FLOATS (WS_SCAL + 64)
// BIG aliased region: phase 1 = padded bf16 copies of x; phase 2 = WEP/TEP + BT/THP
#define WS_BIG     ZERO_FLOATS
#define XB_EN      WS_BIG                       // 512*30080 u16 = 7,700,480 f
#define XB_CN      (WS_BIG + 7700480)           // 512*20096 u16 = 5,144,576 f
#define WEP_EN     WS_BIG                       // 4,812,800 f
#define WEP_CN     (WS_BIG + 4812800)           // 3,215,360 f
#define TEP        (WS_BIG + 4812800 + 3215360) // 20,480 f
#define BT_EN      (WS_BIG + 8048640)           // 30080*128 u16 = 1,925,120 f
#define BT_CN      (BT_EN + 1925120)            // 20096*128 u16 = 1,286,144 f
#define THP_EN     (BT_CN + 1286144)            // 512*128 u16 = 32,768 f
#define THP_CN     (THP_EN + 32768)
#define AFTER_BIG  (WS_BIG + 12845056)
#define W1T_EN     AFTER_BIG                    // 512*30080 u16 = 7,700,480 f
#define W1T_CN     (W1T_EN + 7700480)           // 512*20096 u16 = 5,144,576 f
#define W2T_EN     (W1T_CN + 5144576)
#define W2T_CN     (W2T_EN + 131072)
#define H1B_EN     (W2T_CN + 131072)
#define H1B_CN     (H1B_EN + 131072)
#define WN2_EN     (H1B_CN + 131072)            // 30080
#define WN2_CN     (WN2_EN + 30080)             // 20096
#define TN2        (WN2_CN + 20096)             // 128
#define WS_TNBUF   (TN2 + 128)                  // 51200
#define WS_TNT     (WS_TNBUF + 51200)           // 30000
#define WS_CTOP    (WS_TNT + 30000)             // 10000
#define WS_COLSUM_EN (WS_CTOP + 10000)          // 128
#define WS_COLSUM_CN (WS_COLSUM_EN + 128)

// ---------------- output layout (float offsets) ----------------
#define OUT_THETA_EN 5
#define OUT_THETA_CN (OUT_THETA_EN + 51200)
#define OUT_BETA_EN  (OUT_THETA_CN + 51200)
#define OUT_BETA_CN  (OUT_BETA_EN + 3000000)

__device__ __forceinline__ float waveReduceSum(float v) {
    #pragma unroll
    for (int o = 32; o > 0; o >>= 1) v += __shfl_down(v, o);
    return v;
}

__device__ __forceinline__ unsigned short f2bf(float f) {
    unsigned int u = __float_as_uint(f);
    u = (u + 0x7FFFu + ((u >> 16) & 1u)) >> 16;   // RNE
    return (unsigned short)u;
}

// async global->LDS, 16 B per lane: LDS dest = wave-uniform base + lane*16
__device__ __forceinline__ void gl2lds16(const unsigned short* g, unsigned short* l) {
    __builtin_amdgcn_global_load_lds(
        (const __attribute__((address_space(1))) u32*)g,
        (__attribute__((address_space(3))) u32*)l, 16, 0, 0);
}

// ================= device cores =================

// f32 -> bf16 cast with column zero-padding (256 thr, 8 elems/thr)
__device__ __forceinline__ void cast_pad_core(const float* __restrict__ src,
                                              unsigned short* __restrict__ dst,
                                              int cols, int colsPad, int nx, int vb)
{
    int row = vb / nx, cb = vb - row * nx;
    int col = (cb * 256 + (int)threadIdx.x) * 8;
    if (col >= colsPad) return;
    u16x8 o = {0,0,0,0,0,0,0,0};
    if (col < cols) {
        float4 a = *(const float4*)&src[(size_t)row * cols + col];
        float4 b = *(const float4*)&src[(size_t)row * cols + col + 4];
        o = (u16x8){ f2bf(a.x), f2bf(a.y), f2bf(a.z), f2bf(a.w),
                     f2bf(b.x), f2bf(b.y), f2bf(b.z), f2bf(b.w) };
    }
    *(u16x8*)&dst[(size_t)row * colsPad + col] = o;
}

// 32x32 transpose+cast tile
__device__ __forceinline__ void transpose_core(const float* __restrict__ src,
                                               unsigned short* __restrict__ dst,
                                               int K, int N, int Kp, int kb, int nb,
                                               float (*tile)[33])
{
    int tx = threadIdx.x & 31, ty4 = threadIdx.x >> 5;
    #pragma unroll
    for (int j = 0; j < 4; ++j) {
        int k = kb + ty4 * 4 + j;
        tile[ty4 * 4 + j][tx] = (k < K) ? src[(size_t)k * N + nb + tx] : 0.f;
    }
    __syncthreads();
    #pragma unroll
    for (int j = 0; j < 4; ++j) {
        int n = nb + ty4 * 4 + j;
        int k = kb + tx;
        if (k < Kp) dst[(size_t)n * Kp + k] = f2bf(tile[tx][ty4 * 4 + j]);
    }
}

// async-staged bf16 MFMA NT gemm core. Tile 128x128, BK=64, 4 waves.
// MODE 0: atomicAdd split-K. MODE 1: direct store. MODE 2: beta epilogue.
template <int MODE>
__device__ __forceinline__ void gemm_core(
    const unsigned short* __restrict__ A, const unsigned short* __restrict__ B,
    float* __restrict__ C, int N, int ldA, int ldB, int kStart, int kEnd,
    int Mreal, const float* __restrict__ an2, const float* __restrict__ bn2,
    int m0, int n0, unsigned short* As, unsigned short* Bs)
{
    const int tid = threadIdx.x;
    const int wave = tid >> 6, lane = tid & 63;
    const int wm = (wave & 1) * 64, wn = (wave >> 1) * 64;
    const int l15 = lane & 15, quad = lane >> 4;
    const int rl = lane >> 3;                 // row within 8-row group
    const int cs = (lane & 7) ^ rl;           // swizzled source chunk (8 elems)

    f32x4 acc[4][4];
    #pragma unroll
    for (int i = 0; i < 4; ++i)
        #pragma unroll
        for (int j = 0; j < 4; ++j)
            acc[i][j] = (f32x4){0.f, 0.f, 0.f, 0.f};

    for (int k0 = kStart; k0 < kEnd; k0 += 64) {
        #pragma unroll
        for (int j = 0; j < 4; ++j) {
            int seg = wave * 4 + j;                       // 0..15
            int r = seg * 8 + rl;                         // 0..127
            gl2lds16(A + (size_t)(m0 + r) * ldA + k0 + cs * 8, &As[seg * 512]);
            gl2lds16(B + (size_t)(n0 + r) * ldB + k0 + cs * 8, &Bs[seg * 512]);
        }
        asm volatile("s_waitcnt vmcnt(0)" ::: "memory");
        __syncthreads();

        #pragma unroll
        for (int kh = 0; kh < 2; ++kh) {
            bf16x8 af[4], bfr[4];
            #pragma unroll
            for (int mi = 0; mi < 4; ++mi) {
                int r = wm + mi * 16 + l15;
                af[mi] = *(const bf16x8*)&As[r * 64 + (((kh << 2) | quad) ^ (r & 7)) * 8];
            }
            #pragma unroll
            for (int ni = 0; ni < 4; ++ni) {
                int r = wn + ni * 16 + l15;
                bfr[ni] = *(const bf16x8*)&Bs[r * 64 + (((kh << 2) | quad) ^ (r & 7)) * 8];
            }
            #pragma unroll
            for (int mi = 0; mi < 4; ++mi)
                #pragma unroll
                for (int ni = 0; ni < 4; ++ni)
                    acc[mi][ni] = __builtin_amdgcn_mfma_f32_16x16x32_bf16(af[mi], bfr[ni], acc[mi][ni], 0, 0, 0);
        }
        __syncthreads();
    }

    #pragma unroll
    for (int mi = 0; mi < 4; ++mi)
        #pragma unroll
        for (int ni = 0; ni < 4; ++ni)
            #pragma unroll
            for (int i = 0; i < 4; ++i) {
                int m = m0 + wm + mi * 16 + quad * 4 + i;
                int n = n0 + wn + ni * 16 + l15;
                if (MODE == 0) {
                    atomicAdd(&C[(size_t)m * N + n], acc[mi][ni][i]);
                } else if (MODE == 1) {
                    C[(size_t)m * N + n] = acc[mi][ni][i];
                } else {
                    if (m < Mreal && n < KT) {
                        float sq = an2[m] + bn2[n] - 2.f * acc[mi][ni][i];
                        C[(size_t)n * Mreal + m] = __expf(-sqrtf(fmaxf(sq, 0.f)));
                    }
                }
            }
}

// recon core: r = bt[V][128] x thp[B][128], fused loss sums
__device__ __forceinline__ void recon_core(
    const unsigned short* __restrict__ A, const unsigned short* __restrict__ B,
    const float* __restrict__ x, int V, float* __restrict__ rows,
    int m0, int n0, unsigned short* As, unsigned short* Bs)
{
    const int tid = threadIdx.x;
    const int wave = tid >> 6, lane = tid & 63;
    const int wm = (wave & 1) * 64, wn = (wave >> 1) * 64;
    const int l15 = lane & 15, quad = lane >> 4;
    const int rl = lane >> 3;
    const int cs = (lane & 7) ^ rl;

    f32x4 acc[4][4];
    #pragma unroll
    for (int i = 0; i < 4; ++i)
        #pragma unroll
        for (int j = 0; j < 4; ++j)
            acc[i][j] = (f32x4){0.f, 0.f, 0.f, 0.f};

    for (int k0 = 0; k0 < 128; k0 += 64) {
        #pragma unroll
        for (int j = 0; j < 4; ++j) {
            int seg = wave * 4 + j;
            int r = seg * 8 + rl;
            gl2lds16(A + (size_t)(m0 + r) * 128 + k0 + cs * 8, &As[seg * 512]);
            gl2lds16(B + (size_t)(n0 + r) * 128 + k0 + cs * 8, &Bs[seg * 512]);
        }
        asm volatile("s_waitcnt vmcnt(0)" ::: "memory");
        __syncthreads();

        #pragma unroll
        for (int kh = 0; kh < 2; ++kh) {
            bf16x8 af[4], bfr[4];
            #pragma unroll
            for (int mi = 0; mi < 4; ++mi) {
                int r = wm + mi * 16 + l15;
                af[mi] = *(const bf16x8*)&As[r * 64 + (((kh << 2) | quad) ^ (r & 7)) * 8];
            }
            #pragma unroll
            for (int ni = 0; ni < 4; ++ni) {
                int r = wn + ni * 16 + l15;
                bfr[ni] = *(const bf16x8*)&Bs[r * 64 + (((kh << 2) | quad) ^ (r & 7)) * 8];
            }
            #pragma unroll
            for (int mi = 0; mi < 4; ++mi)
                #pragma unroll
                for (int ni = 0; ni < 4; ++ni)
                    acc[mi][ni] = __builtin_amdgcn_mfma_f32_16x16x32_bf16(af[mi], bfr[ni], acc[mi][ni], 0, 0, 0);
        }
        __syncthreads();
    }

    #pragma unroll
    for (int ni = 0; ni < 4; ++ni) {
        int b = n0 + wn + ni * 16 + l15;
        float tse = 0.f, tsxr = 0.f, tsx = 0.f;
        #pragma unroll
        for (int mi = 0; mi < 4; ++mi) {
            int v0 = m0 + wm + mi * 16 + quad * 4;
            if (v0 + 3 < V) {
                float4 xv = *(const float4*)&x[(size_t)b * V + v0];
                float xa[4] = {xv.x, xv.y, xv.z, xv.w};
                #pragma unroll
                for (int i = 0; i < 4; ++i) {
                    float r = acc[mi][ni][i];
                    tse += __expf(r);
                    tsxr += xa[i] * r;
                    tsx  += xa[i];
                }
            } else {
                #pragma unroll
                for (int i = 0; i < 4; ++i) {
                    int v = v0 + i;
                    if (v < V) {
                        float xv1 = x[(size_t)b * V + v];
                        float r = acc[mi][ni][i];
                        tse += __expf(r); tsxr += xv1 * r; tsx += xv1;
                    }
                }
            }
        }
        tse  += __shfl_xor(tse, 16);  tse  += __shfl_xor(tse, 32);
        tsxr += __shfl_xor(tsxr, 16); tsxr += __shfl_xor(tsxr, 32);
        tsx  += __shfl_xor(tsx, 16);  tsx  += __shfl_xor(tsx, 32);
        if (quad == 0) {
            atomicAdd(&rows[b], tse);
            atomicAdd(&rows[512 + b], tsxr);
            atomicAdd(&rows[1024 + b], tsx);
        }
    }
}

// wave-based: word_emb row -> [KDP] bf16 padded + sqnorm (4 rows/block)
__device__ __forceinline__ void padcast4_core(const float* __restrict__ src,
                                              unsigned short* __restrict__ dst,
                                              float* __restrict__ n2, int V, int vb)
{
    int w = threadIdx.x >> 6, lane = threadIdx.x & 63;
    int m = vb * 4 + w;
    float sq = 0.f;
    #pragma unroll
    for (int j = 0; j < 5; ++j) {
        int k = lane + j * 64;
        float v = (m < V && k < DIM) ? src[(size_t)m * DIM + k] : 0.f;
        dst[(size_t)m * KDP + k] = f2bf(v);
        sq += v * v;
    }
    sq = waveReduceSum(sq);
    if (lane == 0) n2[m] = sq;
}

// wave-based row-normalize (4 rows/block, cols=DIM)
__device__ __forceinline__ void norm_rows4_core(const float* __restrict__ A,
                                                float* __restrict__ out, int vb)
{
    int w = threadIdx.x >> 6, lane = threadIdx.x & 63;
    int r = vb * 4 + w;
    float s = 0.f;
    for (int d = lane; d < DIM; d += 64) { float a = A[r * DIM + d]; s += a * a; }
    s = waveReduceSum(s);
    s = __shfl(s, 0);
    float inv = 1.0f / fmaxf(sqrtf(s), 1e-8f);
    for (int d = lane; d < DIM; d += 64) out[r * DIM + d] = A[r * DIM + d] * inv;
}

__device__ __forceinline__ void bias_sp_bf16_core(const float* __restrict__ src,
                                                  const float* __restrict__ b,
                                                  unsigned short* __restrict__ dst, int vb)
{
    int i = vb * 256 + threadIdx.x;
    float x = src[i] + b[i & (HID - 1)];
    float sp = fmaxf(x, 0.f) + log1pf(__expf(-fabsf(x)));
    dst[i] = f2bf(sp);
}

__device__ __forceinline__ void bias_sp_f32_core(float* __restrict__ y,
                                                 const float* __restrict__ b, int vb)
{
    int i = vb * 256 + threadIdx.x;
    float x = y[i] + b[i & (HID - 1)];
    y[i] = fmaxf(x, 0.f) + log1pf(__expf(-fabsf(x)));
}

// 256-thread encoder head: threads 0..99 compute mu, 128..227 compute lv
__device__ __forceinline__ void encoder_head_core(
    const float* __restrict__ h2, const float* __restrict__ Wmu, const float* __restrict__ bmu,
    const float* __restrict__ Wlv, const float* __restrict__ blv, const float* __restrict__ eps,
    float* __restrict__ theta_out, float* __restrict__ kl_accum, int i,
    float* hrow, float* red, float* lvb)
{
    int tid = threadIdx.x;
    hrow[tid] = h2[i * HID + tid];
    hrow[tid + 256] = h2[i * HID + tid + 256];
    __syncthreads();
    bool gA = tid < KT;
    bool gB = (tid >= 128) && (tid < 128 + KT);
    int rc = gA ? tid : (tid - 128);
    float acc = 0.f;
    if (gA || gB) {
        const float* W = gA ? Wmu : Wlv;
        #pragma unroll 8
        for (int h = 0; h < HID; ++h) acc += hrow[h] * W[h * KT + rc];
        acc += gA ? bmu[rc] : blv[rc];
    }
    if (gB) lvb[rc] = acc;
    __syncthreads();
    float z = -3.0e38f, kterm = 0.f;
    if (gA) {
        float lv = lvb[rc], mu = acc;
        z = mu + eps[i * KT + rc] * __expf(0.5f * lv);
        kterm = 0.5f * (__expf(lv) + mu * mu - 1.f - lv);
    }
    red[tid] = z; __syncthreads();
    for (int s = 128; s > 0; s >>= 1) { if (tid < s) red[tid] = fmaxf(red[tid], red[tid + s]); __syncthreads(); }
    float zmax = red[0]; __syncthreads();
    float e = gA ? __expf(z - zmax) : 0.f;
    red[tid] = e; __syncthreads();
    for (int s = 128; s > 0; s >>= 1) { if (tid < s) red[tid] += red[tid + s]; __syncthreads(); }
    float esum = red[0]; __syncthreads();
    if (gA) theta_out[i * KT + rc] = e / esum;
    red[tid] = gA ? kterm : 0.f; __syncthreads();
    for (int s = 128; s > 0; s >>= 1) { if (tid < s) red[tid] += red[tid + s]; __syncthreads(); }
    if (tid == 0) atomicAdd(kl_accum, red[0]);
}

__device__ __forceinline__ void colsum_core(const float* __restrict__ bta,
                                            float* __restrict__ cs, int V, int k, float* cw)
{
    int tid = threadIdx.x;
    float s = 0.f;
    for (int v = tid; v < V; v += 256) s += bta[(size_t)k * V + v];
    s = waveReduceSum(s);
    if ((tid & 63) == 0) cw[tid >> 6] = s;
    __syncthreads();
    if (tid == 0) cs[k] = cw[0] + cw[1] + cw[2] + cw[3];
}

__device__ __forceinline__ void normbeta_core(float* __restrict__ beta, const float* __restrict__ cs,
                                              unsigned short* __restrict__ bt, int V, int vb)
{
    int v = vb * 64 + (threadIdx.x & 63);
    int kq = threadIdx.x >> 6;
    unsigned short tmp[32];
    #pragma unroll
    for (int j = 0; j < 32; ++j) {
        int k = kq * 32 + j;
        float val = 0.f;
        if (k < KT && v < V) {
            val = beta[(size_t)k * V + v] * (1.0f / cs[k]);
            beta[(size_t)k * V + v] = val;
        }
        tmp[j] = f2bf(val);
    }
    #pragma unroll
    for (int q = 0; q < 4; ++q)
        *(u16x8*)&bt[(size_t)v * 128 + kq * 32 + q * 8] = *(u16x8*)&tmp[q * 8];
}

__device__ __forceinline__ void theta_pad_core(const float* __restrict__ theta,
                                               unsigned short* __restrict__ thp, int vb)
{
    int idx = vb * 256 + threadIdx.x;
    int b = idx >> 7, k = idx & 127;
    thp[idx] = f2bf(k < KT ? theta[b * KT + k] : 0.f);
}

// wave-based contrastive normalize (4 rows/block)
__device__ __forceinline__ void contrast_prep_core(const float* __restrict__ theta_en,
                                                   const float* __restrict__ theta_cn,
                                                   float* __restrict__ tn, int vb)
{
    int w = threadIdx.x >> 6, lane = threadIdx.x & 63;
    int i = vb * 4 + w;
    const float* src = ((i & 1) == 0) ? theta_en : theta_cn;
    float v0 = (lane < KT) ? src[i * KT + lane] : 0.f;
    int d1 = lane + 64;
    float v1 = (d1 < KT) ? src[i * KT + d1] : 0.f;
    float s = waveReduceSum(v0 * v0 + v1 * v1);
    s = __shfl(s, 0);
    float inv = 1.0f / fmaxf(sqrtf(s), 1e-8f);
    if (lane < KT) tn[i * KT + lane] = v0 * inv;
    if (d1 < KT) tn[i * KT + d1] = v1 * inv;
}

__device__ __forceinline__ void contrast_main_core(const float* __restrict__ tn,
                                                   const int* __restrict__ cid,
                                                   float* __restrict__ scal, int i,
                                                   float* ti, float (*cw)[4])
{
    int tid = threadIdx.x;
    if (tid < KT) ti[tid] = tn[i * KT + tid];
    __syncthreads();
    int ci = cid[i];
    bool vi = ci > 0;
    float pos = 0.f, neg = 0.f, pcnt = 0.f;
    for (int j = tid; j < 512; j += 256) {
        if (j == i) continue;
        float s = 0.f;
        const float4* tj = reinterpret_cast<const float4*>(&tn[j * KT]);
        #pragma unroll
        for (int q = 0; q < 25; ++q) {
            float4 t4 = tj[q];
            s += ti[4 * q] * t4.x + ti[4 * q + 1] * t4.y + ti[4 * q + 2] * t4.z + ti[4 * q + 3] * t4.w;
        }
        float E = __expf(s);
        neg += E;
        if (vi && cid[j] == ci) { pos += E; pcnt += 1.f; }
    }
    pos = waveReduceSum(pos); neg = waveReduceSum(neg); pcnt = waveReduceSum(pcnt);
    int w = tid >> 6;
    if ((tid & 63) == 0) { cw[0][w] = pos; cw[1][w] = neg; cw[2][w] = pcnt; }
    __syncthreads();
    if (tid == 0) {
        float P = 0.f, N = 0.f, PC = 0.f;
        for (int q = 0; q < 4; ++q) { P += cw[0][q]; N += cw[1][q]; PC += cw[2][q]; }
        if (vi && PC > 0.f) {
            atomicAdd(&scal[2], -__logf(P / (P + N + 1e-8f)));
            atomicAdd(&scal[3], 1.0f);
        }
    }
}

__device__ __forceinline__ void ctopic_core(const float* __restrict__ tnt,
                                            float* __restrict__ C, int i, float* ti)
{
    int tid = threadIdx.x;
    for (int d = tid; d < DIM; d += 256) ti[d] = tnt[i * DIM + d];
    __syncthreads();
    for (int j = tid; j < KT; j += 256) {
        float s = 0.f;
        for (int d = 0; d < DIM; ++d) s += ti[d] * tnt[j * DIM + d];
        C[i * KT + j] = 1.0f - s;
    }
}

// role-split sinkhorn: threads 0..99 K-rows, 128..227 K-cols; kk in VGPRs.
__device__ __forceinline__ void sinkhorn_core(const float* __restrict__ C,
                                              float* __restrict__ scal,
                                              float* ub, float* vbuf, float* cw)
{
    const int tid = threadIdx.x;
    const bool gA = (tid < 100);
    const bool gB = (tid >= 128 && tid < 228);
    const int rc = gA ? tid : (tid - 128);

    float kk[100];
    if (gA) {
        #pragma unroll
        for (int j = 0; j < 100; ++j) kk[j] = __expf(-10.f * C[rc * 100 + j]);
    } else if (gB) {
        #pragma unroll
        for (int j = 0; j < 100; ++j) kk[j] = __expf(-10.f * C[j * 100 + rc]);
    }
    if (tid < 128) { ub[tid] = 1.f; vbuf[tid] = 1.f; }
    __syncthreads();

    for (int it = 0; it < 50; ++it) {
        if (gA) {
            float s = 0.f;
            #pragma unroll
            for (int q = 0; q < 25; ++q) {
                float4 v4 = *(const float4*)&vbuf[q * 4];
                s += kk[q*4]*v4.x + kk[q*4+1]*v4.y + kk[q*4+2]*v4.z + kk[q*4+3]*v4.w;
            }
            ub[rc] = 0.01f / (s + 1e-8f);
        }
        __syncthreads();
        if (gB) {
            float s = 0.f;
            #pragma unroll
            for (int q = 0; q < 25; ++q) {
                float4 u4 = *(const float4*)&ub[q * 4];
                s += kk[q*4]*u4.x + kk[q*4+1]*u4.y + kk[q*4+2]*u4.z + kk[q*4+3]*u4.w;
            }
            vbuf[rc] = 0.01f / (s + 1e-8f);
        }
        __syncthreads();
    }

    float part = 0.f;
    if (gA) {
        float u = ub[rc];
        #pragma unroll
        for (int j = 0; j < 100; ++j) {
            float k = kk[j];
            part += u * k * vbuf[j] * (-0.1f * __logf(k));
        }
    }
    part = waveReduceSum(part);
    if ((tid & 63) == 0) cw[tid >> 6] = part;
    __syncthreads();
    if (tid == 0) scal[4] = cw[0] + cw[1] + cw[2] + cw[3];
}

// ================= fused dispatches =================

// D2: casts + transposes (all independent)
__global__ __launch_bounds__(256)
void prep_all_kernel(const float* __restrict__ x_en, const float* __restrict__ x_cn,
                     const float* __restrict__ W1_en, const float* __restrict__ W1_cn,
                     const float* __restrict__ W2_en, const float* __restrict__ W2_cn,
                     unsigned short* xb_en, unsigned short* xb_cn,
                     unsigned short* w1t_en, unsigned short* w1t_cn,
                     unsigned short* w2t_en, unsigned short* w2t_cn)
{
    __shared__ float tile[32][33];
    int vb = blockIdx.x;
    if (vb < 7680) { cast_pad_core(x_en, xb_en, VEN, VENK, 15, vb); }
    else if (vb < 12800) { cast_pad_core(x_cn, xb_cn, VCN, VCNK, 10, vb - 7680); }
    else if (vb < 27840) { int v = vb - 12800; transpose_core(W1_en, w1t_en, VEN, HID, VENK, (v % 940) * 32, (v / 940) * 32, tile); }
    else if (vb < 37888) { int v = vb - 27840; transpose_core(W1_cn, w1t_cn, VCN, HID, VCNK, (v % 628) * 32, (v / 628) * 32, tile); }
    else if (vb < 38144) { int v = vb - 37888; transpose_core(W2_en, w2t_en, HID, HID, HID, (v & 15) * 32, (v >> 4) * 32, tile); }
    else { int v = vb - 38144; transpose_core(W2_cn, w2t_cn, HID, HID, HID, (v & 15) * 32, (v >> 4) * 32, tile); }
}

// D3: gemm1 EN+CN (split-K atomic)
__global__ __launch_bounds__(256)
void gemm1_both_kernel(const unsigned short* __restrict__ xb_en, const unsigned short* __restrict__ w1t_en,
                       float* __restrict__ h1_en,
                       const unsigned short* __restrict__ xb_cn, const unsigned short* __restrict__ w1t_cn,
                       float* __restrict__ h1_cn)
{
    __shared__ __align__(16) unsigned short As[128 * 64];
    __shared__ __align__(16) unsigned short Bs[128 * 64];
    int vb = blockIdx.x;
    if (vb < 752) {
        int z = vb >> 4, xy = vb & 15;
        gemm_core<0>(xb_en, w1t_en, h1_en, HID, VENK, VENK, z * 640, min(z * 640 + 640, VENK),
                     0, nullptr, nullptr, (xy & 3) * 128, (xy >> 2) * 128, As, Bs);
    } else {
        int v = vb - 752;
        int z = v >> 4, xy = v & 15;
        gemm_core<0>(xb_cn, w1t_cn, h1_cn, HID, VCNK, VCNK, z * 640, min(z * 640 + 640, VCNK),
                     0, nullptr, nullptr, (xy & 3) * 128, (xy >> 2) * 128, As, Bs);
    }
}

// D4: bias+softplus->bf16 EN+CN
__global__ __launch_bounds__(256)
void bias1_both_kernel(const float* __restrict__ h1_en, const float* __restrict__ b1_en,
                       unsigned short* __restrict__ h1b_en,
                       const float* __restrict__ h1_cn, const float* __restrict__ b1_cn,
                       unsigned short* __restrict__ h1b_cn)
{
    int vb = blockIdx.x;
    if (vb < 1024) bias_sp_bf16_core(h1_en, b1_en, h1b_en, vb);
    else bias_sp_bf16_core(h1_cn, b1_cn, h1b_cn, vb - 1024);
}

// D5: gemm2 EN+CN + padcast (we_en/we_cn/te) + norm_rows(te)
__global__ __launch_bounds__(256)
void d5_kernel(const unsigned short* __restrict__ h1b_en, const unsigned short* __restrict__ w2t_en,
               float* __restrict__ h2_en,
               const unsigned short* __restrict__ h1b_cn, const unsigned short* __restrict__ w2t_cn,
               float* __restrict__ h2_cn,
               const float* __restrict__ we_en, unsigned short* __restrict__ wep_en, float* __restrict__ wn2_en,
               const float* __restrict__ we_cn, unsigned short* __restrict__ wep_cn, float* __restrict__ wn2_cn,
               const float* __restrict__ te, unsigned short* __restrict__ tep, float* __restrict__ tn2,
               float* __restrict__ tnt)
{
    __shared__ __align__(16) unsigned short As[128 * 64];
    __shared__ __align__(16) unsigned short Bs[128 * 64];
    int vb = blockIdx.x;
    if (vb < 16) {
        gemm_core<1>(h1b_en, w2t_en, h2_en, HID, HID, HID, 0, HID,
                     0, nullptr, nullptr, (vb & 3) * 128, (vb >> 2) * 128, As, Bs);
    } else if (vb < 32) {
        int v = vb - 16;
        gemm_core<1>(h1b_cn, w2t_cn, h2_cn, HID, HID, HID, 0, HID,
                     0, nullptr, nullptr, (v & 3) * 128, (v >> 2) * 128, As, Bs);
    }
    else if (vb < 7552) padcast4_core(we_en, wep_en, wn2_en, VEN, vb - 32);
    else if (vb < 12576) padcast4_core(we_cn, wep_cn, wn2_cn, VCN, vb - 7552);
    else if (vb < 12608) padcast4_core(te, tep, tn2, KT, vb - 12576);
    else norm_rows4_core(te, tnt, vb - 12608);
}

// D6: bias2 EN+CN + ctopic + beta gemms EN+CN
__global__ __launch_bounds__(256)
void d6_kernel(float* __restrict__ h2_en, const float* __restrict__ b2_en,
               float* __restrict__ h2_cn, const float* __restrict__ b2_cn,
               const float* __restrict__ tnt, float* __restrict__ ctop,
               const unsigned short* __restrict__ wep_en, const unsigned short* __restrict__ tep,
               float* __restrict__ beta_en, const float* __restrict__ wn2_en, const float* __restrict__ tn2,
               const unsigned short* __restrict__ wep_cn, float* __restrict__ beta_cn,
               const float* __restrict__ wn2_cn)
{
    __shared__ __align__(16) unsigned short As[128 * 64];
    __shared__ __align__(16) unsigned short Bs[128 * 64];
    __shared__ float ti[DIM];
    int vb = blockIdx.x;
    if (vb < 1024) bias_sp_f32_core(h2_en, b2_en, vb);
    else if (vb < 2048) bias_sp_f32_core(h2_cn, b2_cn, vb - 1024);
    else if (vb < 2148) ctopic_core(tnt, ctop, vb - 2048, ti);
    else if (vb < 2383) {
        gemm_core<2>(wep_en, tep, beta_en, 128, KDP, KDP, 0, KDP,
                     VEN, wn2_en, tn2, (vb - 2148) * 128, 0, As, Bs);
    } else {
        gemm_core<2>(wep_cn, tep, beta_cn, 128, KDP, KDP, 0, KDP,
                     VCN, wn2_cn, tn2, (vb - 2383) * 128, 0, As, Bs);
    }
}

// D7: encoder heads EN+CN + colsums + sinkhorn
__global__ __launch_bounds__(256)
void d7_kernel(const float* __restrict__ h2_en, const float* __restrict__ Wmu_en,
               const float* __restrict__ bmu_en, const float* __restrict__ Wlv_en,
               const float* __restrict__ blv_en, const float* __restrict__ eps_en,
               float* __restrict__ theta_en,
               const float* __restrict__ h2_cn, const float* __restrict__ Wmu_cn,
               const float* __restrict__ bmu_cn, const float* __restrict__ Wlv_cn,
               const float* __restrict__ blv_cn, const float* __restrict__ eps_cn,
               float* __restrict__ theta_cn,
               const float* __restrict__ beta_en, float* __restrict__ cs_en,
               const float* __restrict__ beta_cn, float* __restrict__ cs_cn,
               const float* __restrict__ ctop, float* __restrict__ scal)
{
    __shared__ float hrow[HID];
    __shared__ float red[256];
    __shared__ float lvb[128];
    __shared__ float cw[4];
    int vb = blockIdx.x;
    if (vb < 512) encoder_head_core(h2_en, Wmu_en, bmu_en, Wlv_en, blv_en, eps_en, theta_en, &scal[0], vb, hrow, red, lvb);
    else if (vb < 1024) encoder_head_core(h2_cn, Wmu_cn, bmu_cn, Wlv_cn, blv_cn, eps_cn, theta_cn, &scal[1], vb - 512, hrow, red, lvb);
    else if (vb < 1124) colsum_core(beta_en, cs_en, VEN, vb - 1024, cw);
    else if (vb < 1224) colsum_core(beta_cn, cs_cn, VCN, vb - 1124, cw);
    else sinkhorn_core(ctop, scal, red, lvb, cw);   // reuse red[0:128) as ub, lvb as vb
}

// D8: normbeta EN+CN + theta_pad EN+CN + contrast_prep
__global__ __launch_bounds__(256)
void d8_kernel(float* __restrict__ beta_en, const float* __restrict__ cs_en, unsigned short* __restrict__ bt_en,
               float* __restrict__ beta_cn, const float* __restrict__ cs_cn, unsigned short* __restrict__ bt_cn,
               const float* __restrict__ theta_en, unsigned short* __restrict__ thp_en,
               const float* __restrict__ theta_cn, unsigned short* __restrict__ thp_cn,
               float* __restrict__ tn)
{
    int vb = blockIdx.x;
    if (vb < 470) normbeta_core(beta_en, cs_en, bt_en, VEN, vb);
    else if (vb < 784) normbeta_core(beta_cn, cs_cn, bt_cn, VCN, vb - 470);
    else if (vb < 1040) theta_pad_core(theta_en, thp_en, vb - 784);
    else if (vb < 1296) theta_pad_core(theta_cn, thp_cn, vb - 1040);
    else contrast_prep_core(theta_en, theta_cn, tn, vb - 1296);
}

// D9: recon EN+CN + contrast_main
__global__ __launch_bounds__(256)
void d9_kernel(const unsigned short* __restrict__ bt_en, const unsigned short* __restrict__ thp_en,
               const float* __restrict__ x_en, float* __restrict__ rows_en,
               const unsigned short* __restrict__ bt_cn, const unsigned short* __restrict__ thp_cn,
               const float* __restrict__ x_cn, float* __restrict__ rows_cn,
               const float* __restrict__ tn, const int* __restrict__ cid, float* __restrict__ scal)
{
    __shared__ __align__(16) unsigned short As[128 * 64];
    __shared__ __align__(16) unsigned short Bs[128 * 64];
    __shared__ float ti[KT];
    __shared__ float cw[3][4];
    int vb = blockIdx.x;
    if (vb < 940) recon_core(bt_en, thp_en, x_en, VEN, rows_en, (vb % 235) * 128, (vb / 235) * 128, As, Bs);
    else if (vb < 1568) { int v = vb - 940; recon_core(bt_cn, thp_cn, x_cn, VCN, rows_cn, (v % 157) * 128, (v / 157) * 128, As, Bs); }
    else contrast_main_core(tn, cid, scal, vb - 1568, ti, cw);
}

// D10: recon finalize (both sides) + final combine, one block
__global__ __launch_bounds__(256)
void finalize_kernel(const float* __restrict__ rows_en, const float* __restrict__ rows_cn,
                     float* __restrict__ scal, float* __restrict__ out)
{
    __shared__ float cw[4];
    int tid = threadIdx.x;
    #pragma unroll
    for (int side = 0; side < 2; ++side) {
        const float* rows = side ? rows_cn : rows_en;
        float s = 0.f;
        for (int r = tid; r < 512; r += 256) {
            float se = rows[r], sxr = rows[512 + r], sx = rows[1024 + r];
            s += __logf(se) * sx - sxr;
        }
        s = waveReduceSum(s);
        if ((tid & 63) == 0) cw[tid >> 6] = s;
        __syncthreads();
        if (tid == 0) scal[5 + side] = cw[0] + cw[1] + cw[2] + cw[3];
        __syncthreads();
    }
    if (tid == 0) {
        const float invB = 1.0f / 512.0f;
        float tm_en = scal[5] * invB + scal[0] * invB;
        float tm_cn = scal[6] * invB + scal[1] * invB;
        float contrast = scal[2] / (scal[3] + 1e-8f);
        float align = scal[4];
        out[0] = tm_en + tm_cn + contrast + align;
        out[1] = tm_en;
        out[2] = tm_cn;
        out[3] = contrast;
        out[4] = align;
    }
}

// ================= launch =================
extern "C" void kernel_launch(void* const* d_in, const int* in_sizes, int n_in,
                              void* d_out_v, int out_size, void* d_ws, size_t ws_size,
                              hipStream_t stream)
{
    const float* x_en   = (const float*)d_in[0];
    const float* x_cn   = (const float*)d_in[1];
    const int*   cid    = (const int*)  d_in[2];
    const float* eps_en = (const float*)d_in[3];
    const float* eps_cn = (const float*)d_in[4];
    const float* W1_en  = (const float*)d_in[5];
    const float* b1_en  = (const float*)d_in[6];
    const float* W2_en  = (const float*)d_in[7];
    const float* b2_en  = (const float*)d_in[8];
    const float* Wmu_en = (const float*)d_in[9];
    const float* bmu_en = (const float*)d_in[10];
    const float* Wlv_en = (const float*)d_in[11];
    const float* blv_en = (const float*)d_in[12];
    const float* W1_cn  = (const float*)d_in[13];
    const float* b1_cn  = (const float*)d_in[14];
    const float* W2_cn  = (const float*)d_in[15];
    const float* b2_cn  = (const float*)d_in[16];
    const float* Wmu_cn = (const float*)d_in[17];
    const float* bmu_cn = (const float*)d_in[18];
    const float* Wlv_cn = (const float*)d_in[19];
    const float* blv_cn = (const float*)d_in[20];
    const float* we_en  = (const float*)d_in[21];
    const float* we_cn  = (const float*)d_in[22];
    const float* te     = (const float*)d_in[23];
    float* out = (float*)d_out_v;
    float* ws  = (float*)d_ws;

    unsigned short* w1t_en = (unsigned short*)(ws + W1T_EN);
    unsigned short* w1t_cn = (unsigned short*)(ws + W1T_CN);
    unsigned short* w2t_en = (unsigned short*)(ws + W2T_EN);
    unsigned short* w2t_cn = (unsigned short*)(ws + W2T_CN);
    unsigned short* h1b_en = (unsigned short*)(ws + H1B_EN);
    unsigned short* h1b_cn = (unsigned short*)(ws + H1B_CN);
    unsigned short* xb_en  = (unsigned short*)(ws + XB_EN);
    unsigned short* xb_cn  = (unsigned short*)(ws + XB_CN);
    unsigned short* wep_en = (unsigned short*)(ws + WEP_EN);
    unsigned short* wep_cn = (unsigned short*)(ws + WEP_CN);
    unsigned short* tep    = (unsigned short*)(ws + TEP);
    unsigned short* bt_en  = (unsigned short*)(ws + BT_EN);
    unsigned short* bt_cn  = (unsigned short*)(ws + BT_CN);
    unsigned short* thp_en = (unsigned short*)(ws + THP_EN);
    unsigned short* thp_cn = (unsigned short*)(ws + THP_CN);

    hipMemsetAsync(d_ws, 0, (size_t)ZERO_FLOATS * sizeof(float), stream);

    prep_all_kernel<<<38400, 256, 0, stream>>>(x_en, x_cn, W1_en, W1_cn, W2_en, W2_cn,
                                               xb_en, xb_cn, w1t_en, w1t_cn, w2t_en, w2t_cn);

    gemm1_both_kernel<<<1264, 256, 0, stream>>>(xb_en, w1t_en, ws + WS_H1_EN,
                                                xb_cn, w1t_cn, ws + WS_H1_CN);

    bias1_both_kernel<<<2048, 256, 0, stream>>>(ws + WS_H1_EN, b1_en, h1b_en,
                                                ws + WS_H1_CN, b1_cn, h1b_cn);

    d5_kernel<<<12633, 256, 0, stream>>>(h1b_en, w2t_en, ws + WS_H2_EN,
                                         h1b_cn, w2t_cn, ws + WS_H2_CN,
                                         we_en, wep_en, ws + WN2_EN,
                                         we_cn, wep_cn, ws + WN2_CN,
                                         te, tep, ws + TN2, ws + WS_TNT);

    d6_kernel<<<2540, 256, 0, stream>>>(ws + WS_H2_EN, b2_en, ws + WS_H2_CN, b2_cn,
                                        ws + WS_TNT, ws + WS_CTOP,
                                        wep_en, tep, out + OUT_BETA_EN, ws + WN2_EN, ws + TN2,
                                        wep_cn, out + OUT_BETA_CN, ws + WN2_CN);

    d7_kernel<<<1225, 256, 0, stream>>>(ws + WS_H2_EN, Wmu_en, bmu_en, Wlv_en, blv_en, eps_en,
                                        out + OUT_THETA_EN,
                                        ws + WS_H2_CN, Wmu_cn, bmu_cn, Wlv_cn, blv_cn, eps_cn,
                                        out + OUT_THETA_CN,
                                        out + OUT_BETA_EN, ws + WS_COLSUM_EN,
                                        out + OUT_BETA_CN, ws + WS_COLSUM_CN,
                                        ws + WS_CTOP, ws + WS_SCAL);

    d8_kernel<<<1424, 256, 0, stream>>>(out + OUT_BETA_EN, ws + WS_COLSUM_EN, bt_en,
                                        out + OUT_BETA_CN, ws + WS_COLSUM_CN, bt_cn,
                                        out + OUT_THETA_EN, thp_en,
                                        out + OUT_THETA_CN, thp_cn,
                                        ws + WS_TNBUF);

    d9_kernel<<<2080, 256, 0, stream>>>(bt_en, thp_en, x_en, ws + WS_ROWS_EN,
                                        bt_cn, thp_cn, x_cn, ws + WS_ROWS_CN,
                                        ws + WS_TNBUF, cid, ws + WS_SCAL);

    finalize_kernel<<<1, 256, 0, stream>>>(ws + WS_ROWS_EN, ws + WS_ROWS_CN, ws + WS_SCAL, out);
}